// Round 8
// baseline (448.433 us; speedup 1.0000x reference)
//
#include <hip/hip_runtime.h>
#include <hip/hip_bf16.h>
#include <stdint.h>

#define S_LEN 4096
#define EMB   1024
#define NH    8
#define HD    128

typedef __bf16 bf16x8 __attribute__((ext_vector_type(8)));
typedef float  f32x4  __attribute__((ext_vector_type(4)));

__device__ __forceinline__ unsigned short f2bf(float f) {
  unsigned int u = __float_as_uint(f);
  u += 0x7fffu + ((u >> 16) & 1u);
  return (unsigned short)(u >> 16);
}
__device__ __forceinline__ float bf2f(unsigned short u) {
  return __uint_as_float(((unsigned int)u) << 16);
}

typedef __attribute__((address_space(3))) void lds_void_t;
typedef const __attribute__((address_space(1))) void gbl_void_t;

__device__ __forceinline__ void load_lds16(const void* g, void* l) {
  __builtin_amdgcn_global_load_lds((gbl_void_t*)g, (lds_void_t*)l, 16, 0, 0);
}

// ---------------- weight transpose+convert: dst[n][k] = bf16(src[k][n]) ----------------
__global__ __launch_bounds__(256) void conv_w(const float* wq, const float* wk, const float* wv,
                                              const float* wo, unsigned short* wT, unsigned short* woT,
                                              unsigned short* wkm, unsigned short* wkl) {
  int z = blockIdx.z;
  const float* src = (z == 0) ? wq : (z == 1) ? wk : (z == 2) ? wv : wo;
  unsigned short* dst = (z == 3) ? woT : (wT + (size_t)z * 1024 * 1024);
  __shared__ float tl[32][33];
  int tx = threadIdx.x & 31, ty = threadIdx.x >> 5;
  int c0 = blockIdx.x * 32, r0 = blockIdx.y * 32;
#pragma unroll
  for (int i = 0; i < 4; ++i)
    tl[ty + 8 * i][tx] = src[(size_t)(r0 + ty + 8 * i) * 1024 + c0 + tx];
  __syncthreads();
#pragma unroll
  for (int i = 0; i < 4; ++i) {
    float v = tl[tx][ty + 8 * i];
    unsigned short h = f2bf(v);
    size_t o = (size_t)(c0 + ty + 8 * i) * 1024 + r0 + tx;
    dst[o] = h;
    if (z == 1) {
      float r1 = v - bf2f(h);
      unsigned short m = f2bf(r1);
      wkm[o] = m;
      wkl[o] = f2bf(r1 - bf2f(m));
    }
  }
}

// ---------------- x convert (3-plane split) + rep-row gather ----------------
__global__ __launch_bounds__(256) void conv_x(const float* x, unsigned short* xh, unsigned short* xm,
                                              unsigned short* xl, float* xrep) {
  int idx = blockIdx.x * 256 + threadIdx.x;
  if (idx < 4194304) {
    float v = x[idx];
    unsigned short h = f2bf(v);
    xh[idx] = h;
    float r1 = v - bf2f(h);
    unsigned short m = f2bf(r1);
    xm[idx] = m;
    xl[idx] = f2bf(r1 - bf2f(m));
  }
  if (idx < 32768) {
    int r = idx >> 10, e = idx & 1023;
    xrep[idx] = x[(size_t)(r * 128 + 127) * 1024 + e];
  }
}

// ---------------- bf16 MFMA GEMM: C[M,N] = A[M,K=1024] * B[N,K=1024]^T ----------------
template <bool BF16OUT>
__global__ __launch_bounds__(256) void gemm_bt(const unsigned short* A, const unsigned short* B,
                                               void* Cv, int N) {
  __shared__ unsigned short Asm[4096];
  __shared__ unsigned short Bsm[4096];
  int tid = threadIdx.x;
  int w = tid >> 6, l = tid & 63, quad = l >> 4, l16 = l & 15;
  int wm = w >> 1, wn = w & 1;
  int m0 = blockIdx.y * 128, n0 = blockIdx.x * 128;
  f32x4 acc[4][4];
  f32x4 z4 = {0.f, 0.f, 0.f, 0.f};
#pragma unroll
  for (int i = 0; i < 4; ++i)
#pragma unroll
    for (int j = 0; j < 4; ++j) acc[i][j] = z4;
  const unsigned short* Ag = A + (size_t)m0 * 1024;
  const unsigned short* Bg = B + (size_t)n0 * 1024;
  int sl = (quad ^ ((l16 >> 1) & 3)) * 8;
  for (int kt = 0; kt < 1024; kt += 32) {
#pragma unroll
    for (int it = 0; it < 2; ++it) {
      int c = it * 256 + tid;
      int row = c >> 2, sg = c & 3;
      int sw = (sg ^ ((row >> 1) & 3)) * 8;
      load_lds16(Ag + (size_t)row * 1024 + kt + sw, &Asm[(it * 256 + (tid & 192)) * 8]);
      load_lds16(Bg + (size_t)row * 1024 + kt + sw, &Bsm[(it * 256 + (tid & 192)) * 8]);
    }
    __syncthreads();
    bf16x8 af[4], bfr[4];
#pragma unroll
    for (int i = 0; i < 4; ++i) {
      af[i]  = *(const bf16x8*)&Asm[(wm * 64 + i * 16 + l16) * 32 + sl];
      bfr[i] = *(const bf16x8*)&Bsm[(wn * 64 + i * 16 + l16) * 32 + sl];
    }
#pragma unroll
    for (int mi = 0; mi < 4; ++mi)
#pragma unroll
      for (int ni = 0; ni < 4; ++ni)
        acc[mi][ni] = __builtin_amdgcn_mfma_f32_16x16x32_bf16(af[mi], bfr[ni], acc[mi][ni], 0, 0, 0);
    __syncthreads();
  }
#pragma unroll
  for (int mi = 0; mi < 4; ++mi)
#pragma unroll
    for (int ni = 0; ni < 4; ++ni)
#pragma unroll
      for (int r = 0; r < 4; ++r) {
        int row = m0 + wm * 64 + mi * 16 + quad * 4 + r;
        int col = n0 + wn * 64 + ni * 16 + l16;
        if (BF16OUT)
          ((unsigned short*)Cv)[(size_t)row * N + col] = f2bf(acc[mi][ni][r]);
        else
          ((float*)Cv)[(size_t)row * N + col] = acc[mi][ni][r];
      }
}

// ---------------- exact K-GEMM via 3-plane bf16 split MFMA ----------------
__global__ __launch_bounds__(256) void kexact(const unsigned short* Ah, const unsigned short* Am,
                                              const unsigned short* Al, const unsigned short* Bh,
                                              const unsigned short* Bm, const unsigned short* Bl,
                                              float* C) {
  __shared__ unsigned short As[3 * 2048];
  __shared__ unsigned short Bs[3 * 4096];
  int tid = threadIdx.x;
  int w = tid >> 6, l = tid & 63, quad = l >> 4, l16 = l & 15;
  int wm = w >> 1, wn = w & 1;
  int m0 = blockIdx.y * 64, n0 = blockIdx.x * 128;
  f32x4 acc[2][4];
  f32x4 z4 = {0.f, 0.f, 0.f, 0.f};
#pragma unroll
  for (int i = 0; i < 2; ++i)
#pragma unroll
    for (int j = 0; j < 4; ++j) acc[i][j] = z4;
  const unsigned short* Aps[3] = {Ah + (size_t)m0 * 1024, Am + (size_t)m0 * 1024, Al + (size_t)m0 * 1024};
  const unsigned short* Bps[3] = {Bh + (size_t)n0 * 1024, Bm + (size_t)n0 * 1024, Bl + (size_t)n0 * 1024};
  int arow = tid >> 2, asg = tid & 3;
  int asw = (asg ^ ((arow >> 1) & 3)) * 8;
  int sl = (quad ^ ((l16 >> 1) & 3)) * 8;
  for (int kt = 0; kt < 1024; kt += 32) {
#pragma unroll
    for (int p = 0; p < 3; ++p) {
      load_lds16(Aps[p] + (size_t)arow * 1024 + kt + asw, &As[p * 2048 + (tid & 192) * 8]);
#pragma unroll
      for (int it = 0; it < 2; ++it) {
        int c = it * 256 + tid;
        int row = c >> 2, sg = c & 3;
        int sw = (sg ^ ((row >> 1) & 3)) * 8;
        load_lds16(Bps[p] + (size_t)row * 1024 + kt + sw,
                   &Bs[p * 4096 + (it * 256 + (tid & 192)) * 8]);
      }
    }
    __syncthreads();
    bf16x8 af[3][2], bfr[3][4];
#pragma unroll
    for (int p = 0; p < 3; ++p) {
#pragma unroll
      for (int i = 0; i < 2; ++i)
        af[p][i] = *(const bf16x8*)&As[p * 2048 + (wm * 32 + i * 16 + l16) * 32 + sl];
#pragma unroll
      for (int j = 0; j < 4; ++j)
        bfr[p][j] = *(const bf16x8*)&Bs[p * 4096 + (wn * 64 + j * 16 + l16) * 32 + sl];
    }
#pragma unroll
    for (int mi = 0; mi < 2; ++mi)
#pragma unroll
      for (int ni = 0; ni < 4; ++ni) {
        f32x4 a = acc[mi][ni];
        a = __builtin_amdgcn_mfma_f32_16x16x32_bf16(af[0][mi], bfr[0][ni], a, 0, 0, 0);
        a = __builtin_amdgcn_mfma_f32_16x16x32_bf16(af[0][mi], bfr[1][ni], a, 0, 0, 0);
        a = __builtin_amdgcn_mfma_f32_16x16x32_bf16(af[1][mi], bfr[0][ni], a, 0, 0, 0);
        a = __builtin_amdgcn_mfma_f32_16x16x32_bf16(af[1][mi], bfr[1][ni], a, 0, 0, 0);
        a = __builtin_amdgcn_mfma_f32_16x16x32_bf16(af[0][mi], bfr[2][ni], a, 0, 0, 0);
        a = __builtin_amdgcn_mfma_f32_16x16x32_bf16(af[2][mi], bfr[0][ni], a, 0, 0, 0);
        acc[mi][ni] = a;
      }
    __syncthreads();
  }
#pragma unroll
  for (int mi = 0; mi < 2; ++mi)
#pragma unroll
    for (int ni = 0; ni < 4; ++ni)
#pragma unroll
      for (int r = 0; r < 4; ++r) {
        int row = m0 + wm * 32 + mi * 16 + quad * 4 + r;
        int col = n0 + wn * 64 + ni * 16 + l16;
        C[(size_t)row * 1024 + col] = acc[mi][ni][r];
      }
}

// ---------------- qrep GEMM ----------------
__global__ __launch_bounds__(256) void qrep_gemm(const float* xrep, const float* wq, float* qparts) {
  int n0 = blockIdx.x * 32;
  int p  = blockIdx.y;
  int k0 = p * 128;
  int tid = threadIdx.x;
  __shared__ float xs[32 * 132];
  __shared__ float wsm[128 * 36];
#pragma unroll
  for (int i = 0; i < 4; ++i) {
    int c = tid + 256 * i;
    int m = c >> 5, kc = (c & 31) * 4;
    *(f32x4*)&xs[m * 132 + kc] = *(const f32x4*)&xrep[(size_t)m * 1024 + k0 + kc];
  }
#pragma unroll
  for (int i = 0; i < 4; ++i) {
    int c = tid + 256 * i;
    int k = c >> 3, n = (c & 7) * 4;
    *(f32x4*)&wsm[k * 36 + n] = *(const f32x4*)&wq[(size_t)(k0 + k) * 1024 + n0 + n];
  }
  __syncthreads();
#pragma unroll
  for (int i = 0; i < 4; ++i) {
    int o = tid + 256 * i;
    int m = o >> 5, n = o & 31;
    float acc = 0.f;
#pragma unroll 16
    for (int k = 0; k < 128; ++k) acc += xs[m * 132 + k] * wsm[k * 36 + n];
    qparts[((size_t)p * 32 + m) * 1024 + n0 + n] = acc;
  }
}

__global__ __launch_bounds__(256) void qsum(const float* qparts, float* qrep) {
  int i = blockIdx.x * 256 + threadIdx.x;
  float s = 0.f;
#pragma unroll
  for (int p = 0; p < 8; ++p) s += qparts[(size_t)p * 32768 + i];
  qrep[i] = s;
}

// ---------------- RoPE + pack ----------------
__global__ __launch_bounds__(256) void rope_pack(const unsigned short* qkv, const float* cosb,
                                                 const float* sinb, unsigned short* q_bf,
                                                 unsigned short* k_bf, unsigned short* vT) {
  int h = blockIdx.y;
  int s0 = blockIdx.x * 64;
  int tid = threadIdx.x;
  __shared__ unsigned short vt[128 * 66];
  for (int idx = tid; idx < 4096; idx += 256) {
    int r = idx >> 6, j = idx & 63;
    int s = s0 + r;
    float c = cosb[s * 64 + j], sn = sinb[s * 64 + j];
    const unsigned short* row = qkv + (size_t)s * 3072 + h * 128;
    size_t ob = ((size_t)h * S_LEN + s) * 128;
    float a = bf2f(row[j]), b = bf2f(row[j + 64]);
    q_bf[ob + j]      = f2bf(a * c - b * sn);
    q_bf[ob + j + 64] = f2bf(b * c + a * sn);
    a = bf2f(row[1024 + j]); b = bf2f(row[1024 + j + 64]);
    k_bf[ob + j]      = f2bf(a * c - b * sn);
    k_bf[ob + j + 64] = f2bf(b * c + a * sn);
  }
  for (int idx = tid; idx < 8192; idx += 256) {
    int r = idx >> 7, d = idx & 127;
    vt[d * 66 + r] = qkv[(size_t)(s0 + r) * 3072 + 2048 + h * 128 + d];
  }
  __syncthreads();
  for (int idx = tid; idx < 8192; idx += 256) {
    int d = idx >> 6, c = idx & 63;
    vT[((size_t)h * 128 + d) * S_LEN + s0 + c] = vt[d * 66 + c];
  }
}

// ---------------- in-place RoPE on fp32 K ----------------
__global__ __launch_bounds__(256) void rope_k_kernel(float* kf, const float* cosb, const float* sinb) {
  int idx = blockIdx.x * 256 + threadIdx.x;
  int s = idx >> 9;
  int rem = idx & 511;
  int h = rem >> 6, j = rem & 63;
  float c = cosb[s * 64 + j], sn = sinb[s * 64 + j];
  size_t e1 = (size_t)s * 1024 + h * 128 + j;
  float a = kf[e1], b = kf[e1 + 64];
  kf[e1]      = a * c - b * sn;
  kf[e1 + 64] = b * c + a * sn;
}

// ---------------- flash attention: Q-tile 128, K-tile 64, 16x16 MFMA, 3 blocks/CU ----------------
// grid (32 qt, 8 h, 3 split). Waves own 32 rows (mi=2). P in private LDS buffer -> 2 barriers/iter.
__global__ __launch_bounds__(256, 3) void flash_attn(const unsigned short* q_bf,
                                                     const unsigned short* k_bf,
                                                     const unsigned short* vT,
                                                     unsigned short* Opart,
                                                     float* mpart, float* lpart) {
  int qt = blockIdx.x, h = blockIdx.y, split = blockIdx.z;
  int tid = threadIdx.x, w = tid >> 6, l = tid & 63, quad = l >> 4, l16 = l & 15;
  __shared__ unsigned short Ks[4096 * 2];   // 16KB: [kc4][key64][32dims] swizzled
  __shared__ unsigned short Vs[4096 * 2];   // 16KB: [kc2][d128][32keys] swizzled
  __shared__ unsigned short Ps[128 * 72];   // 18KB: [row128][64keys + pad8]
  const unsigned short* qbase = q_bf + (size_t)h * S_LEN * 128;
  const unsigned short* kbase = k_bf + (size_t)h * S_LEN * 128;
  const unsigned short* vbase = vT + (size_t)h * 128 * S_LEN;
  int sl = (quad ^ ((l16 >> 1) & 3)) * 8;
  bf16x8 qf[2][4];
#pragma unroll
  for (int mi = 0; mi < 2; ++mi)
#pragma unroll
    for (int kc = 0; kc < 4; ++kc) {
      int row = qt * 128 + w * 32 + mi * 16 + l16;
      qf[mi][kc] = *(const bf16x8*)&qbase[(size_t)row * 128 + kc * 32 + quad * 8];
    }
  f32x4 z4 = {0.f, 0.f, 0.f, 0.f};
  f32x4 o[2][8];
#pragma unroll
  for (int mi = 0; mi < 2; ++mi)
#pragma unroll
    for (int i = 0; i < 8; ++i) o[mi][i] = z4;
  float mrow[2][4], lrow[2][4];
#pragma unroll
  for (int mi = 0; mi < 2; ++mi)
#pragma unroll
    for (int r = 0; r < 4; ++r) { mrow[mi][r] = -3e38f; lrow[mi][r] = 0.f; }
  const float sc2 = 0.12751712f;  // (1/sqrt(128)) * log2(e)
  int ntiles = 2 * (qt + 1);      // 64-key tiles
  for (int j = split; j < ntiles; j += 3) {
    // stage K (16KB) and V^T (16KB)
#pragma unroll
    for (int it = 0; it < 4; ++it) {
      int c = it * 256 + tid;
      int kck = c >> 8, cck = c & 255, rr = cck >> 2;
      int sgk = c & 3;
      int swk = (sgk ^ ((rr >> 1) & 3)) * 8;
      load_lds16(kbase + (size_t)(j * 64 + rr) * 128 + kck * 32 + swk,
                 &Ks[(it * 256 + (tid & 192)) * 8]);
      int kcv = c >> 9, ccv = c & 511, d = ccv >> 2;
      int sgv = c & 3;
      int swv = (sgv ^ ((d >> 1) & 3)) * 8;
      load_lds16(vbase + (size_t)d * S_LEN + j * 64 + kcv * 32 + swv,
                 &Vs[(it * 256 + (tid & 192)) * 8]);
    }
    __syncthreads();
    // QK^T over 4 kc chunks of 32 dims; kf reused for both mi
    f32x4 sa[2][4];
#pragma unroll
    for (int mi = 0; mi < 2; ++mi)
#pragma unroll
      for (int i = 0; i < 4; ++i) sa[mi][i] = z4;
#pragma unroll
    for (int kc = 0; kc < 4; ++kc) {
#pragma unroll
      for (int ni = 0; ni < 4; ++ni) {
        bf16x8 kf = *(const bf16x8*)&Ks[kc * 2048 + (ni * 16 + l16) * 32 + sl];
        sa[0][ni] = __builtin_amdgcn_mfma_f32_16x16x32_bf16(qf[0][kc], kf, sa[0][ni], 0, 0, 0);
        sa[1][ni] = __builtin_amdgcn_mfma_f32_16x16x32_bf16(qf[1][kc], kf, sa[1][ni], 0, 0, 0);
      }
    }
    bool diag = (j >= 2 * qt);
#pragma unroll
    for (int mi = 0; mi < 2; ++mi)
#pragma unroll
      for (int r = 0; r < 4; ++r) {
        int qrow = qt * 128 + w * 32 + mi * 16 + quad * 4 + r;
        float vmax = -3e38f;
#pragma unroll
        for (int ni = 0; ni < 4; ++ni) {
          int key = j * 64 + ni * 16 + l16;
          float v = sa[mi][ni][r] * sc2;
          if (diag && key > qrow) v = -1e10f;
          sa[mi][ni][r] = v;
          vmax = fmaxf(vmax, v);
        }
        vmax = fmaxf(vmax, __shfl_xor(vmax, 1));
        vmax = fmaxf(vmax, __shfl_xor(vmax, 2));
        vmax = fmaxf(vmax, __shfl_xor(vmax, 4));
        vmax = fmaxf(vmax, __shfl_xor(vmax, 8));
        float mnew = fmaxf(mrow[mi][r], vmax);
        float alpha = exp2f(mrow[mi][r] - mnew);
        mrow[mi][r] = mnew;
        float rsum = 0.f;
#pragma unroll
        for (int ni = 0; ni < 4; ++ni) {
          float p = exp2f(sa[mi][ni][r] - mnew);
          sa[mi][ni][r] = p;
          rsum += p;
        }
        rsum += __shfl_xor(rsum, 1);
        rsum += __shfl_xor(rsum, 2);
        rsum += __shfl_xor(rsum, 4);
        rsum += __shfl_xor(rsum, 8);
        lrow[mi][r] = lrow[mi][r] * alpha + rsum;
#pragma unroll
        for (int nd = 0; nd < 8; ++nd) o[mi][nd][r] *= alpha;
      }
    // P -> private Ps rows (within-wave only; no barriers needed)
#pragma unroll
    for (int mi = 0; mi < 2; ++mi)
#pragma unroll
      for (int ni = 0; ni < 4; ++ni)
#pragma unroll
        for (int r = 0; r < 4; ++r) {
          int prow = w * 32 + mi * 16 + quad * 4 + r;
          Ps[prow * 72 + ni * 16 + l16] = f2bf(sa[mi][ni][r]);
        }
    // PV over 2 kc chunks of 32 keys; vf reused for both mi
#pragma unroll
    for (int kc = 0; kc < 2; ++kc) {
      bf16x8 pf0 = *(const bf16x8*)&Ps[(w * 32 + l16) * 72 + kc * 32 + quad * 8];
      bf16x8 pf1 = *(const bf16x8*)&Ps[(w * 32 + 16 + l16) * 72 + kc * 32 + quad * 8];
#pragma unroll
      for (int nd = 0; nd < 8; ++nd) {
        bf16x8 vf = *(const bf16x8*)&Vs[kc * 4096 + (nd * 16 + l16) * 32 + sl];
        o[0][nd] = __builtin_amdgcn_mfma_f32_16x16x32_bf16(pf0, vf, o[0][nd], 0, 0, 0);
        o[1][nd] = __builtin_amdgcn_mfma_f32_16x16x32_bf16(pf1, vf, o[1][nd], 0, 0, 0);
      }
    }
    __syncthreads();  // protect Ks/Vs before next staging
  }
  size_t pbase = (size_t)(split * 8 + h) * 4096 + (size_t)qt * 128;
#pragma unroll
  for (int mi = 0; mi < 2; ++mi)
#pragma unroll
    for (int r = 0; r < 4; ++r) {
      int lr = w * 32 + mi * 16 + quad * 4 + r;
#pragma unroll
      for (int nd = 0; nd < 8; ++nd)
        Opart[(pbase + lr) * 128 + nd * 16 + l16] = f2bf(o[mi][nd][r]);
      if (l16 == 0) {
        mpart[pbase + lr] = mrow[mi][r];
        lpart[pbase + lr] = lrow[mi][r];
      }
    }
}

// ---------------- combine the three key-splits ----------------
__global__ __launch_bounds__(256) void combine(const unsigned short* Opart, const float* mpart,
                                               const float* lpart, unsigned short* attn) {
  int idx = blockIdx.x * 256 + threadIdx.x;  // 8*4096*128
  int h = idx >> 19;
  int rem = idx & 524287;
  int row = rem >> 7, d = rem & 127;
  int rb = h * 4096 + row;
  float m0 = mpart[rb], m1 = mpart[32768 + rb], m2 = mpart[65536 + rb];
  float m = fmaxf(m0, fmaxf(m1, m2));
  float a0 = exp2f(m0 - m), a1 = exp2f(m1 - m), a2 = exp2f(m2 - m);
  float denom = a0 * lpart[rb] + a1 * lpart[32768 + rb] + a2 * lpart[65536 + rb];
  float num = a0 * bf2f(Opart[(size_t)rb * 128 + d]) +
              a1 * bf2f(Opart[(size_t)(32768 + rb) * 128 + d]) +
              a2 * bf2f(Opart[(size_t)(65536 + rb) * 128 + d]);
  attn[(size_t)row * 1024 + h * 128 + d] = f2bf(num / denom);
}

// ---------------- rep-logit tile scores ----------------
__global__ __launch_bounds__(256) void rep_scores(const float* krope, const float* qrep,
                                                  const float* cosb, const float* sinb,
                                                  float* scores) {
  int tt = blockIdx.x, h = blockIdx.y;
  int tid = threadIdx.x;
  __shared__ float Kt[128 * 129];
  __shared__ float qv[32 * 128];
  __shared__ float lg[32 * 128];
  for (int idx = tid; idx < 16384; idx += 256) {
    int r = idx >> 7, c = idx & 127;
    Kt[r * 129 + c] = krope[(size_t)(tt * 128 + r) * 1024 + h * 128 + c];
  }
  for (int idx = tid; idx < 2048; idx += 256) {
    int rep = idx >> 6, j = idx & 63;
    int sq = rep * 128 + 127;
    float a = qrep[(size_t)rep * 1024 + h * 128 + j];
    float b = qrep[(size_t)rep * 1024 + h * 128 + j + 64];
    float c = cosb[sq * 64 + j], sn = sinb[sq * 64 + j];
    qv[rep * 128 + j]      = a * c - b * sn;
    qv[rep * 128 + j + 64] = b * c + a * sn;
  }
  __syncthreads();
  int key = tid >> 1, half = tid & 1;
  float kreg[64];
#pragma unroll
  for (int d = 0; d < 64; ++d) kreg[d] = Kt[key * 129 + half * 64 + d];
  for (int rep = 0; rep < 32; ++rep) {
    const float* q = &qv[rep * 128 + half * 64];
    float dot = 0.f;
#pragma unroll
    for (int d = 0; d < 64; ++d) dot += kreg[d] * q[d];
    dot += __shfl_xor(dot, 1);
    if (half == 0) lg[rep * 128 + key] = dot;
  }
  __syncthreads();
  int rep = tid >> 3, chunk = tid & 7;
  float m = -3e38f;
#pragma unroll
  for (int i = 0; i < 16; ++i) m = fmaxf(m, lg[rep * 128 + chunk * 16 + i]);
  m = fmaxf(m, __shfl_xor(m, 1));
  m = fmaxf(m, __shfl_xor(m, 2));
  m = fmaxf(m, __shfl_xor(m, 4));
  if (chunk == 0) scores[((size_t)h * 32 + rep) * 32 + tt] = m;
}

// ---------------- top-8 selection ----------------
__global__ __launch_bounds__(256) void select_topk(const float* scores, float* out_idx) {
  int tid = threadIdx.x;
  int h = tid >> 5, t = tid & 31;
  float vals[32];
#pragma unroll
  for (int tt = 0; tt < 32; ++tt)
    vals[tt] = (tt <= t) ? scores[((size_t)h * 32 + t) * 32 + tt] : -3.0e38f;
  int base = (h * 32 + t) * 8;
  for (int i = 0; i < 8; ++i) {
    float best = -3.4e38f;
    int bi = 0;
#pragma unroll
    for (int c = 0; c < 32; ++c)
      if (vals[c] > best) { best = vals[c]; bi = c; }
    out_idx[base + i] = (float)bi;
    vals[bi] = -3.4e38f;
  }
}

extern "C" void kernel_launch(void* const* d_in, const int* in_sizes, int n_in,
                              void* d_out, int out_size, void* d_ws, size_t ws_size,
                              hipStream_t stream) {
  (void)in_sizes; (void)n_in; (void)out_size; (void)ws_size;
  const float* x    = (const float*)d_in[0];
  const float* wq   = (const float*)d_in[1];
  const float* wk   = (const float*)d_in[2];
  const float* wv   = (const float*)d_in[3];
  const float* wo   = (const float*)d_in[4];
  const float* cosb = (const float*)d_in[5];
  const float* sinb = (const float*)d_in[6];
  float* out = (float*)d_out;
  char* ws = (char*)d_ws;

  unsigned short* x_bf   = (unsigned short*)(ws);              //  0 ..  8 MB (= xh plane)
  unsigned short* wT     = (unsigned short*)(ws + 8388608);    //  8 .. 14 MB
  unsigned short* woT    = (unsigned short*)(ws + 14680064);   // 14 .. 16 MB
  unsigned short* qkv_bf = (unsigned short*)(ws + 16777216);   // 16 .. 40 MB (dead after rope_pack)
  unsigned short* Opart  = (unsigned short*)(ws + 16777216);   // 16 .. 40 MB (3x8x4096x128 bf16)
  unsigned short* q_bf   = (unsigned short*)(ws + 41943040);   // 40 .. 48 MB
  unsigned short* k_bf   = (unsigned short*)(ws + 50331648);   // 48 .. 56 MB
  unsigned short* vT     = (unsigned short*)(ws + 58720256);   // 56 .. 64 MB
  unsigned short* attn   = (unsigned short*)(ws + 58720256);   // reuse vT region after flash
  unsigned short* xm     = (unsigned short*)(ws + 41943040);   // transient, overlaps q_bf
  unsigned short* xl     = (unsigned short*)(ws + 50331648);   // transient, overlaps k_bf
  unsigned short* wkm    = (unsigned short*)(ws + 58720256);   // transient, overlaps vT
  unsigned short* wkl    = (unsigned short*)(ws + 60817408);   // transient, overlaps vT+2MB
  float*          kf32   = (float*)(ws + 67108864);            // 64 .. 80 MB
  float*          xrep   = (float*)(ws + 83886080);            // 80.00 MB
  float*          qrep   = (float*)(ws + 84017152);            // 80.125 MB
  float*          qparts = (float*)(ws + 84148224);            // 80.25 .. 81.25 MB (dead after qsum)
  float*          mpart  = (float*)(ws + 84148224);            // reuse qparts: 3x8x4096x4 = 384KB
  float*          lpart  = (float*)(ws + 84541440);            // +384KB
  float*          scores = (float*)(ws + 85196800);            // 81.25 MB + 32 KB

  unsigned short* wkh = wT + (size_t)1 * 1024 * 1024;

  conv_w<<<dim3(32, 32, 4), 256, 0, stream>>>(wq, wk, wv, wo, wT, woT, wkm, wkl);
  conv_x<<<dim3(16384), 256, 0, stream>>>(x, x_bf, xm, xl, xrep);
  gemm_bt<true><<<dim3(24, 32), 256, 0, stream>>>(x_bf, wT, qkv_bf, 3072);
  kexact<<<dim3(8, 64), 256, 0, stream>>>(x_bf, xm, xl, wkh, wkm, wkl, kf32);
  qrep_gemm<<<dim3(32, 8), 256, 0, stream>>>(xrep, wq, qparts);
  qsum<<<dim3(128), 256, 0, stream>>>(qparts, qrep);
  rope_pack<<<dim3(64, 8), 256, 0, stream>>>(qkv_bf, cosb, sinb, q_bf, k_bf, vT);
  rope_k_kernel<<<dim3(8192), 256, 0, stream>>>(kf32, cosb, sinb);
  flash_attn<<<dim3(32, 8, 3), 256, 0, stream>>>(q_bf, k_bf, vT, Opart, mpart, lpart);
  combine<<<dim3(16384), 256, 0, stream>>>(Opart, mpart, lpart, attn);
  gemm_bt<false><<<dim3(8, 32), 256, 0, stream>>>(attn, woT, out, 1024);
  rep_scores<<<dim3(32, 8), 256, 0, stream>>>(kf32, qrep, cosb, sinb, scores);
  select_topk<<<dim3(1), 256, 0, stream>>>(scores, out + 4194304);
}

// Round 9
// 401.009 us; speedup vs baseline: 1.1183x; 1.1183x over previous
//
#include <hip/hip_runtime.h>
#include <hip/hip_bf16.h>
#include <stdint.h>

#define S_LEN 4096
#define EMB   1024
#define NH    8
#define HD    128

typedef __bf16 bf16x8 __attribute__((ext_vector_type(8)));
typedef float  f32x4  __attribute__((ext_vector_type(4)));

__device__ __forceinline__ unsigned short f2bf(float f) {
  unsigned int u = __float_as_uint(f);
  u += 0x7fffu + ((u >> 16) & 1u);
  return (unsigned short)(u >> 16);
}
__device__ __forceinline__ float bf2f(unsigned short u) {
  return __uint_as_float(((unsigned int)u) << 16);
}

typedef __attribute__((address_space(3))) void lds_void_t;
typedef const __attribute__((address_space(1))) void gbl_void_t;

__device__ __forceinline__ void load_lds16(const void* g, void* l) {
  __builtin_amdgcn_global_load_lds((gbl_void_t*)g, (lds_void_t*)l, 16, 0, 0);
}

// ---------------- weight transpose+convert: dst[n][k] = bf16(src[k][n]) ----------------
__global__ __launch_bounds__(256) void conv_w(const float* wq, const float* wk, const float* wv,
                                              const float* wo, unsigned short* wT, unsigned short* woT,
                                              unsigned short* wkm, unsigned short* wkl) {
  int z = blockIdx.z;
  const float* src = (z == 0) ? wq : (z == 1) ? wk : (z == 2) ? wv : wo;
  unsigned short* dst = (z == 3) ? woT : (wT + (size_t)z * 1024 * 1024);
  __shared__ float tl[32][33];
  int tx = threadIdx.x & 31, ty = threadIdx.x >> 5;
  int c0 = blockIdx.x * 32, r0 = blockIdx.y * 32;
#pragma unroll
  for (int i = 0; i < 4; ++i)
    tl[ty + 8 * i][tx] = src[(size_t)(r0 + ty + 8 * i) * 1024 + c0 + tx];
  __syncthreads();
#pragma unroll
  for (int i = 0; i < 4; ++i) {
    float v = tl[tx][ty + 8 * i];
    unsigned short h = f2bf(v);
    size_t o = (size_t)(c0 + ty + 8 * i) * 1024 + r0 + tx;
    dst[o] = h;
    if (z == 1) {
      float r1 = v - bf2f(h);
      unsigned short m = f2bf(r1);
      wkm[o] = m;
      wkl[o] = f2bf(r1 - bf2f(m));
    }
  }
}

// ---------------- x convert (3-plane split) + rep-row gather ----------------
__global__ __launch_bounds__(256) void conv_x(const float* x, unsigned short* xh, unsigned short* xm,
                                              unsigned short* xl, float* xrep) {
  int idx = blockIdx.x * 256 + threadIdx.x;
  if (idx < 4194304) {
    float v = x[idx];
    unsigned short h = f2bf(v);
    xh[idx] = h;
    float r1 = v - bf2f(h);
    unsigned short m = f2bf(r1);
    xm[idx] = m;
    xl[idx] = f2bf(r1 - bf2f(m));
  }
  if (idx < 32768) {
    int r = idx >> 10, e = idx & 1023;
    xrep[idx] = x[(size_t)(r * 128 + 127) * 1024 + e];
  }
}

// ---------------- bf16 MFMA GEMM: C[M,N] = A[M,K=1024] * B[N,K=1024]^T ----------------
template <bool BF16OUT>
__global__ __launch_bounds__(256) void gemm_bt(const unsigned short* A, const unsigned short* B,
                                               void* Cv, int N) {
  __shared__ unsigned short Asm[4096];
  __shared__ unsigned short Bsm[4096];
  int tid = threadIdx.x;
  int w = tid >> 6, l = tid & 63, quad = l >> 4, l16 = l & 15;
  int wm = w >> 1, wn = w & 1;
  int m0 = blockIdx.y * 128, n0 = blockIdx.x * 128;
  f32x4 acc[4][4];
  f32x4 z4 = {0.f, 0.f, 0.f, 0.f};
#pragma unroll
  for (int i = 0; i < 4; ++i)
#pragma unroll
    for (int j = 0; j < 4; ++j) acc[i][j] = z4;
  const unsigned short* Ag = A + (size_t)m0 * 1024;
  const unsigned short* Bg = B + (size_t)n0 * 1024;
  int sl = (quad ^ ((l16 >> 1) & 3)) * 8;
  for (int kt = 0; kt < 1024; kt += 32) {
#pragma unroll
    for (int it = 0; it < 2; ++it) {
      int c = it * 256 + tid;
      int row = c >> 2, sg = c & 3;
      int sw = (sg ^ ((row >> 1) & 3)) * 8;
      load_lds16(Ag + (size_t)row * 1024 + kt + sw, &Asm[(it * 256 + (tid & 192)) * 8]);
      load_lds16(Bg + (size_t)row * 1024 + kt + sw, &Bsm[(it * 256 + (tid & 192)) * 8]);
    }
    __syncthreads();
    bf16x8 af[4], bfr[4];
#pragma unroll
    for (int i = 0; i < 4; ++i) {
      af[i]  = *(const bf16x8*)&Asm[(wm * 64 + i * 16 + l16) * 32 + sl];
      bfr[i] = *(const bf16x8*)&Bsm[(wn * 64 + i * 16 + l16) * 32 + sl];
    }
#pragma unroll
    for (int mi = 0; mi < 4; ++mi)
#pragma unroll
      for (int ni = 0; ni < 4; ++ni)
        acc[mi][ni] = __builtin_amdgcn_mfma_f32_16x16x32_bf16(af[mi], bfr[ni], acc[mi][ni], 0, 0, 0);
    __syncthreads();
  }
#pragma unroll
  for (int mi = 0; mi < 4; ++mi)
#pragma unroll
    for (int ni = 0; ni < 4; ++ni)
#pragma unroll
      for (int r = 0; r < 4; ++r) {
        int row = m0 + wm * 64 + mi * 16 + quad * 4 + r;
        int col = n0 + wn * 64 + ni * 16 + l16;
        if (BF16OUT)
          ((unsigned short*)Cv)[(size_t)row * N + col] = f2bf(acc[mi][ni][r]);
        else
          ((float*)Cv)[(size_t)row * N + col] = acc[mi][ni][r];
      }
}

// ---------------- exact K-GEMM via 3-plane bf16 split MFMA ----------------
__global__ __launch_bounds__(256) void kexact(const unsigned short* Ah, const unsigned short* Am,
                                              const unsigned short* Al, const unsigned short* Bh,
                                              const unsigned short* Bm, const unsigned short* Bl,
                                              float* C) {
  __shared__ unsigned short As[3 * 2048];
  __shared__ unsigned short Bs[3 * 4096];
  int tid = threadIdx.x;
  int w = tid >> 6, l = tid & 63, quad = l >> 4, l16 = l & 15;
  int wm = w >> 1, wn = w & 1;
  int m0 = blockIdx.y * 64, n0 = blockIdx.x * 128;
  f32x4 acc[2][4];
  f32x4 z4 = {0.f, 0.f, 0.f, 0.f};
#pragma unroll
  for (int i = 0; i < 2; ++i)
#pragma unroll
    for (int j = 0; j < 4; ++j) acc[i][j] = z4;
  const unsigned short* Aps[3] = {Ah + (size_t)m0 * 1024, Am + (size_t)m0 * 1024, Al + (size_t)m0 * 1024};
  const unsigned short* Bps[3] = {Bh + (size_t)n0 * 1024, Bm + (size_t)n0 * 1024, Bl + (size_t)n0 * 1024};
  int arow = tid >> 2, asg = tid & 3;
  int asw = (asg ^ ((arow >> 1) & 3)) * 8;
  int sl = (quad ^ ((l16 >> 1) & 3)) * 8;
  for (int kt = 0; kt < 1024; kt += 32) {
#pragma unroll
    for (int p = 0; p < 3; ++p) {
      load_lds16(Aps[p] + (size_t)arow * 1024 + kt + asw, &As[p * 2048 + (tid & 192) * 8]);
#pragma unroll
      for (int it = 0; it < 2; ++it) {
        int c = it * 256 + tid;
        int row = c >> 2, sg = c & 3;
        int sw = (sg ^ ((row >> 1) & 3)) * 8;
        load_lds16(Bps[p] + (size_t)row * 1024 + kt + sw,
                   &Bs[p * 4096 + (it * 256 + (tid & 192)) * 8]);
      }
    }
    __syncthreads();
    bf16x8 af[3][2], bfr[3][4];
#pragma unroll
    for (int p = 0; p < 3; ++p) {
#pragma unroll
      for (int i = 0; i < 2; ++i)
        af[p][i] = *(const bf16x8*)&As[p * 2048 + (wm * 32 + i * 16 + l16) * 32 + sl];
#pragma unroll
      for (int j = 0; j < 4; ++j)
        bfr[p][j] = *(const bf16x8*)&Bs[p * 4096 + (wn * 64 + j * 16 + l16) * 32 + sl];
    }
#pragma unroll
    for (int mi = 0; mi < 2; ++mi)
#pragma unroll
      for (int ni = 0; ni < 4; ++ni) {
        f32x4 a = acc[mi][ni];
        a = __builtin_amdgcn_mfma_f32_16x16x32_bf16(af[0][mi], bfr[0][ni], a, 0, 0, 0);
        a = __builtin_amdgcn_mfma_f32_16x16x32_bf16(af[0][mi], bfr[1][ni], a, 0, 0, 0);
        a = __builtin_amdgcn_mfma_f32_16x16x32_bf16(af[1][mi], bfr[0][ni], a, 0, 0, 0);
        a = __builtin_amdgcn_mfma_f32_16x16x32_bf16(af[1][mi], bfr[1][ni], a, 0, 0, 0);
        a = __builtin_amdgcn_mfma_f32_16x16x32_bf16(af[0][mi], bfr[2][ni], a, 0, 0, 0);
        a = __builtin_amdgcn_mfma_f32_16x16x32_bf16(af[2][mi], bfr[0][ni], a, 0, 0, 0);
        acc[mi][ni] = a;
      }
    __syncthreads();
  }
#pragma unroll
  for (int mi = 0; mi < 2; ++mi)
#pragma unroll
    for (int ni = 0; ni < 4; ++ni)
#pragma unroll
      for (int r = 0; r < 4; ++r) {
        int row = m0 + wm * 32 + mi * 16 + quad * 4 + r;
        int col = n0 + wn * 64 + ni * 16 + l16;
        C[(size_t)row * 1024 + col] = acc[mi][ni][r];
      }
}

// ---------------- qrep GEMM ----------------
__global__ __launch_bounds__(256) void qrep_gemm(const float* xrep, const float* wq, float* qparts) {
  int n0 = blockIdx.x * 32;
  int p  = blockIdx.y;
  int k0 = p * 128;
  int tid = threadIdx.x;
  __shared__ float xs[32 * 132];
  __shared__ float wsm[128 * 36];
#pragma unroll
  for (int i = 0; i < 4; ++i) {
    int c = tid + 256 * i;
    int m = c >> 5, kc = (c & 31) * 4;
    *(f32x4*)&xs[m * 132 + kc] = *(const f32x4*)&xrep[(size_t)m * 1024 + k0 + kc];
  }
#pragma unroll
  for (int i = 0; i < 4; ++i) {
    int c = tid + 256 * i;
    int k = c >> 3, n = (c & 7) * 4;
    *(f32x4*)&wsm[k * 36 + n] = *(const f32x4*)&wq[(size_t)(k0 + k) * 1024 + n0 + n];
  }
  __syncthreads();
#pragma unroll
  for (int i = 0; i < 4; ++i) {
    int o = tid + 256 * i;
    int m = o >> 5, n = o & 31;
    float acc = 0.f;
#pragma unroll 16
    for (int k = 0; k < 128; ++k) acc += xs[m * 132 + k] * wsm[k * 36 + n];
    qparts[((size_t)p * 32 + m) * 1024 + n0 + n] = acc;
  }
}

__global__ __launch_bounds__(256) void qsum(const float* qparts, float* qrep) {
  int i = blockIdx.x * 256 + threadIdx.x;
  float s = 0.f;
#pragma unroll
  for (int p = 0; p < 8; ++p) s += qparts[(size_t)p * 32768 + i];
  qrep[i] = s;
}

// ---------------- RoPE + pack ----------------
__global__ __launch_bounds__(256) void rope_pack(const unsigned short* qkv, const float* cosb,
                                                 const float* sinb, unsigned short* q_bf,
                                                 unsigned short* k_bf, unsigned short* vT) {
  int h = blockIdx.y;
  int s0 = blockIdx.x * 64;
  int tid = threadIdx.x;
  __shared__ unsigned short vt[128 * 66];
  for (int idx = tid; idx < 4096; idx += 256) {
    int r = idx >> 6, j = idx & 63;
    int s = s0 + r;
    float c = cosb[s * 64 + j], sn = sinb[s * 64 + j];
    const unsigned short* row = qkv + (size_t)s * 3072 + h * 128;
    size_t ob = ((size_t)h * S_LEN + s) * 128;
    float a = bf2f(row[j]), b = bf2f(row[j + 64]);
    q_bf[ob + j]      = f2bf(a * c - b * sn);
    q_bf[ob + j + 64] = f2bf(b * c + a * sn);
    a = bf2f(row[1024 + j]); b = bf2f(row[1024 + j + 64]);
    k_bf[ob + j]      = f2bf(a * c - b * sn);
    k_bf[ob + j + 64] = f2bf(b * c + a * sn);
  }
  for (int idx = tid; idx < 8192; idx += 256) {
    int r = idx >> 7, d = idx & 127;
    vt[d * 66 + r] = qkv[(size_t)(s0 + r) * 3072 + 2048 + h * 128 + d];
  }
  __syncthreads();
  for (int idx = tid; idx < 8192; idx += 256) {
    int d = idx >> 6, c = idx & 63;
    vT[((size_t)h * 128 + d) * S_LEN + s0 + c] = vt[d * 66 + c];
  }
}

// ---------------- in-place RoPE on fp32 K ----------------
__global__ __launch_bounds__(256) void rope_k_kernel(float* kf, const float* cosb, const float* sinb) {
  int idx = blockIdx.x * 256 + threadIdx.x;
  int s = idx >> 9;
  int rem = idx & 511;
  int h = rem >> 6, j = rem & 63;
  float c = cosb[s * 64 + j], sn = sinb[s * 64 + j];
  size_t e1 = (size_t)s * 1024 + h * 128 + j;
  float a = kf[e1], b = kf[e1 + 64];
  kf[e1]      = a * c - b * sn;
  kf[e1 + 64] = b * c + a * sn;
}

// ---------------- flash attention: Q64/K128, 16x16 MFMA, XCD-pinned, qt-paired ----------------
// grid (8 h, 64 y, 2 split); XCD = h (linear%8); CU slot = y%32 pairs qt=c with qt=63-c.
__global__ __launch_bounds__(256) void flash_attn(const unsigned short* q_bf, const unsigned short* k_bf,
                                                  const unsigned short* vT, unsigned short* Opart,
                                                  float* mpart, float* lpart) {
  int h = blockIdx.x;
  int y = blockIdx.y;
  int qt = (y < 32) ? y : 95 - y;   // pair long+short per CU slot
  int split = blockIdx.z;
  int tid = threadIdx.x, w = tid >> 6, l = tid & 63, quad = l >> 4, l16 = l & 15;
  __shared__ unsigned short Ks[16384]; // K tile [kc][key][32] swizzled; reused for P
  __shared__ unsigned short Vs[16384]; // V^T tile [kc][d][32keys] swizzled
  const unsigned short* qbase = q_bf + (size_t)h * S_LEN * 128;
  const unsigned short* kbase = k_bf + (size_t)h * S_LEN * 128;
  const unsigned short* vbase = vT + (size_t)h * 128 * S_LEN;
  int sl = (quad ^ ((l16 >> 1) & 3)) * 8;
  bf16x8 qf[4];
#pragma unroll
  for (int kc = 0; kc < 4; ++kc) {
    int row = qt * 64 + w * 16 + l16;
    qf[kc] = *(const bf16x8*)&qbase[(size_t)row * 128 + kc * 32 + quad * 8];
  }
  f32x4 z4 = {0.f, 0.f, 0.f, 0.f};
  f32x4 o[8];
#pragma unroll
  for (int i = 0; i < 8; ++i) o[i] = z4;
  float mrow[4], lrow[4];
#pragma unroll
  for (int r = 0; r < 4; ++r) { mrow[r] = -3e38f; lrow[r] = 0.f; }
  const float sc2 = 0.12751712f;  // (1/sqrt(128)) * log2(e)
  int niter = (qt >> 1) + 1;
  int jmax = niter - 1;
  int half0 = (niter + 1) >> 1;
  int jlo = split ? half0 : 0;
  int jhi = split ? niter : half0;
  for (int j = jlo; j < jhi; ++j) {
#pragma unroll
    for (int it = 0; it < 8; ++it) {
      int c = it * 256 + tid;
      int kc = c >> 9, cc = c & 511, rr = cc >> 2, sg = cc & 3;
      int sw = (sg ^ ((rr >> 1) & 3)) * 8;
      load_lds16(kbase + (size_t)(j * 128 + rr) * 128 + kc * 32 + sw,
                 &Ks[(it * 256 + (tid & 192)) * 8]);
      load_lds16(vbase + (size_t)rr * S_LEN + j * 128 + kc * 32 + sw,
                 &Vs[(it * 256 + (tid & 192)) * 8]);
    }
    __syncthreads();
    f32x4 sa[8];
#pragma unroll
    for (int i = 0; i < 8; ++i) sa[i] = z4;
#pragma unroll
    for (int kc = 0; kc < 4; ++kc) {
      bf16x8 kf[8];
#pragma unroll
      for (int ni = 0; ni < 8; ++ni)
        kf[ni] = *(const bf16x8*)&Ks[kc * 4096 + (ni * 16 + l16) * 32 + sl];
#pragma unroll
      for (int ni = 0; ni < 8; ++ni)
        sa[ni] = __builtin_amdgcn_mfma_f32_16x16x32_bf16(qf[kc], kf[ni], sa[ni], 0, 0, 0);
    }
    bool diag = (j == jmax);
    float rmax[4];
#pragma unroll
    for (int r = 0; r < 4; ++r) rmax[r] = -3e38f;
#pragma unroll
    for (int ni = 0; ni < 8; ++ni) {
      int key = j * 128 + ni * 16 + l16;
#pragma unroll
      for (int r = 0; r < 4; ++r) {
        int qrow = qt * 64 + w * 16 + quad * 4 + r;
        float v = sa[ni][r] * sc2;
        if (diag && key > qrow) v = -1e10f;
        sa[ni][r] = v;
        rmax[r] = fmaxf(rmax[r], v);
      }
    }
#pragma unroll
    for (int r = 0; r < 4; ++r) {
      float v = rmax[r];
      v = fmaxf(v, __shfl_xor(v, 1));
      v = fmaxf(v, __shfl_xor(v, 2));
      v = fmaxf(v, __shfl_xor(v, 4));
      v = fmaxf(v, __shfl_xor(v, 8));
      float mnew = fmaxf(mrow[r], v);
      float alpha = exp2f(mrow[r] - mnew);
      mrow[r] = mnew;
      float rsum = 0.f;
#pragma unroll
      for (int ni = 0; ni < 8; ++ni) {
        float p = exp2f(sa[ni][r] - mnew);
        sa[ni][r] = p;
        rsum += p;
      }
      rsum += __shfl_xor(rsum, 1);
      rsum += __shfl_xor(rsum, 2);
      rsum += __shfl_xor(rsum, 4);
      rsum += __shfl_xor(rsum, 8);
      lrow[r] = lrow[r] * alpha + rsum;
#pragma unroll
      for (int nd = 0; nd < 8; ++nd) o[nd][r] *= alpha;
    }
    __syncthreads();
#pragma unroll
    for (int ni = 0; ni < 8; ++ni) {
      int key = ni * 16 + l16, kc = key >> 5, col = key & 31;
#pragma unroll
      for (int r = 0; r < 4; ++r) {
        int qr = w * 16 + quad * 4 + r;
        int slot = (col >> 3) ^ ((qr >> 1) & 3);
        Ks[kc * 2048 + qr * 32 + slot * 8 + (col & 7)] = f2bf(sa[ni][r]);
      }
    }
    __syncthreads();
#pragma unroll
    for (int kc = 0; kc < 4; ++kc) {
      bf16x8 pf = *(const bf16x8*)&Ks[kc * 2048 + (w * 16 + l16) * 32 + sl];
#pragma unroll
      for (int nd = 0; nd < 8; ++nd) {
        bf16x8 vf = *(const bf16x8*)&Vs[kc * 4096 + (nd * 16 + l16) * 32 + sl];
        o[nd] = __builtin_amdgcn_mfma_f32_16x16x32_bf16(pf, vf, o[nd], 0, 0, 0);
      }
    }
    __syncthreads();
  }
  size_t pbase = (size_t)(split * 8 + h) * 4096 + qt * 64;
#pragma unroll
  for (int r = 0; r < 4; ++r) {
    int lr = w * 16 + quad * 4 + r;
#pragma unroll
    for (int nd = 0; nd < 8; ++nd) {
      int d = nd * 16 + l16;
      Opart[(pbase + lr) * 128 + d] = f2bf(o[nd][r]);
    }
    if (l16 == 0) {
      mpart[pbase + lr] = mrow[r];
      lpart[pbase + lr] = lrow[r];
    }
  }
}

// ---------------- combine the two key-splits ----------------
__global__ __launch_bounds__(256) void combine(const unsigned short* Opart, const float* mpart,
                                               const float* lpart, unsigned short* attn) {
  int idx = blockIdx.x * 256 + threadIdx.x;  // 8*4096*128
  int h = idx >> 19;
  int rem = idx & 524287;
  int row = rem >> 7, d = rem & 127;
  int r0 = h * 4096 + row;
  int r1 = 32768 + r0;
  float m0 = mpart[r0], m1 = mpart[r1];
  float l0 = lpart[r0], l1 = lpart[r1];
  float m = fmaxf(m0, m1);
  float a0 = exp2f(m0 - m), a1 = exp2f(m1 - m);
  float o0 = bf2f(Opart[(size_t)r0 * 128 + d]);
  float o1 = bf2f(Opart[(size_t)r1 * 128 + d]);
  float denom = a0 * l0 + a1 * l1;
  attn[(size_t)row * 1024 + h * 128 + d] = f2bf((a0 * o0 + a1 * o1) / denom);
}

// ---------------- rep-logit tile scores (XCD-pinned: x = head) ----------------
__global__ __launch_bounds__(256) void rep_scores(const float* krope, const float* qrep,
                                                  const float* cosb, const float* sinb,
                                                  float* scores) {
  int h = blockIdx.x, tt = blockIdx.y;
  int tid = threadIdx.x;
  __shared__ float Kt[128 * 129];
  __shared__ float qv[32 * 128];
  __shared__ float lg[32 * 128];
  for (int idx = tid; idx < 16384; idx += 256) {
    int r = idx >> 7, c = idx & 127;
    Kt[r * 129 + c] = krope[(size_t)(tt * 128 + r) * 1024 + h * 128 + c];
  }
  for (int idx = tid; idx < 2048; idx += 256) {
    int rep = idx >> 6, j = idx & 63;
    int sq = rep * 128 + 127;
    float a = qrep[(size_t)rep * 1024 + h * 128 + j];
    float b = qrep[(size_t)rep * 1024 + h * 128 + j + 64];
    float c = cosb[sq * 64 + j], sn = sinb[sq * 64 + j];
    qv[rep * 128 + j]      = a * c - b * sn;
    qv[rep * 128 + j + 64] = b * c + a * sn;
  }
  __syncthreads();
  int key = tid >> 1, half = tid & 1;
  float kreg[64];
#pragma unroll
  for (int d = 0; d < 64; ++d) kreg[d] = Kt[key * 129 + half * 64 + d];
  for (int rep = 0; rep < 32; ++rep) {
    const float* q = &qv[rep * 128 + half * 64];
    float dot = 0.f;
#pragma unroll
    for (int d = 0; d < 64; ++d) dot += kreg[d] * q[d];
    dot += __shfl_xor(dot, 1);
    if (half == 0) lg[rep * 128 + key] = dot;
  }
  __syncthreads();
  int rep = tid >> 3, chunk = tid & 7;
  float m = -3e38f;
#pragma unroll
  for (int i = 0; i < 16; ++i) m = fmaxf(m, lg[rep * 128 + chunk * 16 + i]);
  m = fmaxf(m, __shfl_xor(m, 1));
  m = fmaxf(m, __shfl_xor(m, 2));
  m = fmaxf(m, __shfl_xor(m, 4));
  if (chunk == 0) scores[((size_t)h * 32 + rep) * 32 + tt] = m;
}

// ---------------- top-8 selection ----------------
__global__ __launch_bounds__(256) void select_topk(const float* scores, float* out_idx) {
  int tid = threadIdx.x;
  int h = tid >> 5, t = tid & 31;
  float vals[32];
#pragma unroll
  for (int tt = 0; tt < 32; ++tt)
    vals[tt] = (tt <= t) ? scores[((size_t)h * 32 + t) * 32 + tt] : -3.0e38f;
  int base = (h * 32 + t) * 8;
  for (int i = 0; i < 8; ++i) {
    float best = -3.4e38f;
    int bi = 0;
#pragma unroll
    for (int c = 0; c < 32; ++c)
      if (vals[c] > best) { best = vals[c]; bi = c; }
    out_idx[base + i] = (float)bi;
    vals[bi] = -3.4e38f;
  }
}

extern "C" void kernel_launch(void* const* d_in, const int* in_sizes, int n_in,
                              void* d_out, int out_size, void* d_ws, size_t ws_size,
                              hipStream_t stream) {
  (void)in_sizes; (void)n_in; (void)out_size; (void)ws_size;
  const float* x    = (const float*)d_in[0];
  const float* wq   = (const float*)d_in[1];
  const float* wk   = (const float*)d_in[2];
  const float* wv   = (const float*)d_in[3];
  const float* wo   = (const float*)d_in[4];
  const float* cosb = (const float*)d_in[5];
  const float* sinb = (const float*)d_in[6];
  float* out = (float*)d_out;
  char* ws = (char*)d_ws;

  unsigned short* x_bf   = (unsigned short*)(ws);              //  0 ..  8 MB (= xh plane)
  unsigned short* wT     = (unsigned short*)(ws + 8388608);    //  8 .. 14 MB
  unsigned short* woT    = (unsigned short*)(ws + 14680064);   // 14 .. 16 MB
  unsigned short* qkv_bf = (unsigned short*)(ws + 16777216);   // 16 .. 40 MB (dead after rope_pack)
  unsigned short* attn   = (unsigned short*)(ws + 16777216);   // 16 .. 24 MB
  unsigned short* Opart  = (unsigned short*)(ws + 25165824);   // 24 .. 40 MB (2x8x4096x128 bf16)
  unsigned short* q_bf   = (unsigned short*)(ws + 41943040);   // 40 .. 48 MB
  unsigned short* k_bf   = (unsigned short*)(ws + 50331648);   // 48 .. 56 MB
  unsigned short* vT     = (unsigned short*)(ws + 58720256);   // 56 .. 64 MB
  unsigned short* xm     = (unsigned short*)(ws + 41943040);   // transient, overlaps q_bf
  unsigned short* xl     = (unsigned short*)(ws + 50331648);   // transient, overlaps k_bf
  unsigned short* wkm    = (unsigned short*)(ws + 58720256);   // transient, overlaps vT
  unsigned short* wkl    = (unsigned short*)(ws + 60817408);   // transient, overlaps vT+2MB
  float*          kf32   = (float*)(ws + 67108864);            // 64 .. 80 MB
  float*          xrep   = (float*)(ws + 83886080);            // 80.00 MB
  float*          qrep   = (float*)(ws + 84017152);            // 80.125 MB
  float*          qparts = (float*)(ws + 84148224);            // 80.25 .. 81.25 MB
  float*          scores = (float*)(ws + 85196800);            // 81.25 MB + 32 KB
  float*          mpart  = (float*)(ws + 85229568);            // +256 KB
  float*          lpart  = (float*)(ws + 85491712);            // +256 KB

  unsigned short* wkh = wT + (size_t)1 * 1024 * 1024;

  conv_w<<<dim3(32, 32, 4), 256, 0, stream>>>(wq, wk, wv, wo, wT, woT, wkm, wkl);
  conv_x<<<dim3(16384), 256, 0, stream>>>(x, x_bf, xm, xl, xrep);
  gemm_bt<true><<<dim3(24, 32), 256, 0, stream>>>(x_bf, wT, qkv_bf, 3072);
  kexact<<<dim3(8, 64), 256, 0, stream>>>(x_bf, xm, xl, wkh, wkm, wkl, kf32);
  qrep_gemm<<<dim3(32, 8), 256, 0, stream>>>(xrep, wq, qparts);
  qsum<<<dim3(128), 256, 0, stream>>>(qparts, qrep);
  rope_pack<<<dim3(64, 8), 256, 0, stream>>>(qkv_bf, cosb, sinb, q_bf, k_bf, vT);
  rope_k_kernel<<<dim3(8192), 256, 0, stream>>>(kf32, cosb, sinb);
  flash_attn<<<dim3(8, 64, 2), 256, 0, stream>>>(q_bf, k_bf, vT, Opart, mpart, lpart);
  combine<<<dim3(16384), 256, 0, stream>>>(Opart, mpart, lpart, attn);
  gemm_bt<false><<<dim3(8, 32), 256, 0, stream>>>(attn, woT, out, 1024);
  rep_scores<<<dim3(8, 32), 256, 0, stream>>>(kf32, qrep, cosb, sinb, scores);
  select_topk<<<dim3(1), 256, 0, stream>>>(scores, out + 4194304);
}

// Round 10
// 372.451 us; speedup vs baseline: 1.2040x; 1.0767x over previous
//
#include <hip/hip_runtime.h>
#include <hip/hip_bf16.h>
#include <stdint.h>

#define S_LEN 4096
#define EMB   1024
#define NH    8
#define HD    128

typedef __bf16 bf16x8 __attribute__((ext_vector_type(8)));
typedef float  f32x4  __attribute__((ext_vector_type(4)));

__device__ __forceinline__ unsigned short f2bf(float f) {
  unsigned int u = __float_as_uint(f);
  u += 0x7fffu + ((u >> 16) & 1u);
  return (unsigned short)(u >> 16);
}
__device__ __forceinline__ float bf2f(unsigned short u) {
  return __uint_as_float(((unsigned int)u) << 16);
}

typedef __attribute__((address_space(3))) void lds_void_t;
typedef const __attribute__((address_space(1))) void gbl_void_t;

__device__ __forceinline__ void load_lds16(const void* g, void* l) {
  __builtin_amdgcn_global_load_lds((gbl_void_t*)g, (lds_void_t*)l, 16, 0, 0);
}

// ---------------- weight transpose+convert: dst[n][k] = bf16(src[k][n]) ----------------
// For wk (z==1) additionally emits the mid split plane (transposed) for the exact K path.
__global__ __launch_bounds__(256) void conv_w(const float* wq, const float* wk, const float* wv,
                                              const float* wo, unsigned short* wT, unsigned short* woT,
                                              unsigned short* wkm) {
  int z = blockIdx.z;
  const float* src = (z == 0) ? wq : (z == 1) ? wk : (z == 2) ? wv : wo;
  unsigned short* dst = (z == 3) ? woT : (wT + (size_t)z * 1024 * 1024);
  __shared__ float tl[32][33];
  int tx = threadIdx.x & 31, ty = threadIdx.x >> 5;
  int c0 = blockIdx.x * 32, r0 = blockIdx.y * 32;
#pragma unroll
  for (int i = 0; i < 4; ++i)
    tl[ty + 8 * i][tx] = src[(size_t)(r0 + ty + 8 * i) * 1024 + c0 + tx];
  __syncthreads();
#pragma unroll
  for (int i = 0; i < 4; ++i) {
    float v = tl[tx][ty + 8 * i];
    unsigned short h = f2bf(v);
    size_t o = (size_t)(c0 + ty + 8 * i) * 1024 + r0 + tx;
    dst[o] = h;
    if (z == 1) wkm[o] = f2bf(v - bf2f(h));
  }
}

// ---------------- x convert (2-plane split) + rep-row gather ----------------
__global__ __launch_bounds__(256) void conv_x(const float* x, unsigned short* xh, unsigned short* xm,
                                              float* xrep) {
  int idx = blockIdx.x * 256 + threadIdx.x;
  if (idx < 4194304) {
    float v = x[idx];
    unsigned short h = f2bf(v);
    xh[idx] = h;
    xm[idx] = f2bf(v - bf2f(h));
  }
  if (idx < 32768) {
    int r = idx >> 10, e = idx & 1023;
    xrep[idx] = x[(size_t)(r * 128 + 127) * 1024 + e];
  }
}

// ---------------- bf16 MFMA GEMM: C[M,N] = A[M,K=1024] * B[N,K=1024]^T ----------------
template <bool BF16OUT>
__global__ __launch_bounds__(256) void gemm_bt(const unsigned short* A, const unsigned short* B,
                                               void* Cv, int N) {
  __shared__ unsigned short Asm[4096];
  __shared__ unsigned short Bsm[4096];
  int tid = threadIdx.x;
  int w = tid >> 6, l = tid & 63, quad = l >> 4, l16 = l & 15;
  int wm = w >> 1, wn = w & 1;
  int m0 = blockIdx.y * 128, n0 = blockIdx.x * 128;
  f32x4 acc[4][4];
  f32x4 z4 = {0.f, 0.f, 0.f, 0.f};
#pragma unroll
  for (int i = 0; i < 4; ++i)
#pragma unroll
    for (int j = 0; j < 4; ++j) acc[i][j] = z4;
  const unsigned short* Ag = A + (size_t)m0 * 1024;
  const unsigned short* Bg = B + (size_t)n0 * 1024;
  int sl = (quad ^ ((l16 >> 1) & 3)) * 8;
  for (int kt = 0; kt < 1024; kt += 32) {
#pragma unroll
    for (int it = 0; it < 2; ++it) {
      int c = it * 256 + tid;
      int row = c >> 2, sg = c & 3;
      int sw = (sg ^ ((row >> 1) & 3)) * 8;
      load_lds16(Ag + (size_t)row * 1024 + kt + sw, &Asm[(it * 256 + (tid & 192)) * 8]);
      load_lds16(Bg + (size_t)row * 1024 + kt + sw, &Bsm[(it * 256 + (tid & 192)) * 8]);
    }
    __syncthreads();
    bf16x8 af[4], bfr[4];
#pragma unroll
    for (int i = 0; i < 4; ++i) {
      af[i]  = *(const bf16x8*)&Asm[(wm * 64 + i * 16 + l16) * 32 + sl];
      bfr[i] = *(const bf16x8*)&Bsm[(wn * 64 + i * 16 + l16) * 32 + sl];
    }
#pragma unroll
    for (int mi = 0; mi < 4; ++mi)
#pragma unroll
      for (int ni = 0; ni < 4; ++ni)
        acc[mi][ni] = __builtin_amdgcn_mfma_f32_16x16x32_bf16(af[mi], bfr[ni], acc[mi][ni], 0, 0, 0);
    __syncthreads();
  }
#pragma unroll
  for (int mi = 0; mi < 4; ++mi)
#pragma unroll
    for (int ni = 0; ni < 4; ++ni)
#pragma unroll
      for (int r = 0; r < 4; ++r) {
        int row = m0 + wm * 64 + mi * 16 + quad * 4 + r;
        int col = n0 + wn * 64 + ni * 16 + l16;
        if (BF16OUT)
          ((unsigned short*)Cv)[(size_t)row * N + col] = f2bf(acc[mi][ni][r]);
        else
          ((float*)Cv)[(size_t)row * N + col] = acc[mi][ni][r];
      }
}

// ---------------- exact K-GEMM via 2-plane bf16 split MFMA (hh+hm+mh+mm) ----------------
__global__ __launch_bounds__(256) void kexact(const unsigned short* Ah, const unsigned short* Am,
                                              const unsigned short* Bh, const unsigned short* Bm,
                                              float* C) {
  __shared__ unsigned short As[2 * 2048];
  __shared__ unsigned short Bs[2 * 4096];
  int tid = threadIdx.x;
  int w = tid >> 6, l = tid & 63, quad = l >> 4, l16 = l & 15;
  int wm = w >> 1, wn = w & 1;
  int m0 = blockIdx.y * 64, n0 = blockIdx.x * 128;
  f32x4 acc[2][4];
  f32x4 z4 = {0.f, 0.f, 0.f, 0.f};
#pragma unroll
  for (int i = 0; i < 2; ++i)
#pragma unroll
    for (int j = 0; j < 4; ++j) acc[i][j] = z4;
  const unsigned short* Aps[2] = {Ah + (size_t)m0 * 1024, Am + (size_t)m0 * 1024};
  const unsigned short* Bps[2] = {Bh + (size_t)n0 * 1024, Bm + (size_t)n0 * 1024};
  int arow = tid >> 2, asg = tid & 3;
  int asw = (asg ^ ((arow >> 1) & 3)) * 8;
  int sl = (quad ^ ((l16 >> 1) & 3)) * 8;
  for (int kt = 0; kt < 1024; kt += 32) {
#pragma unroll
    for (int p = 0; p < 2; ++p) {
      load_lds16(Aps[p] + (size_t)arow * 1024 + kt + asw, &As[p * 2048 + (tid & 192) * 8]);
#pragma unroll
      for (int it = 0; it < 2; ++it) {
        int c = it * 256 + tid;
        int row = c >> 2, sg = c & 3;
        int sw = (sg ^ ((row >> 1) & 3)) * 8;
        load_lds16(Bps[p] + (size_t)row * 1024 + kt + sw,
                   &Bs[p * 4096 + (it * 256 + (tid & 192)) * 8]);
      }
    }
    __syncthreads();
    bf16x8 af[2][2], bfr[2][4];
#pragma unroll
    for (int p = 0; p < 2; ++p) {
#pragma unroll
      for (int i = 0; i < 2; ++i)
        af[p][i] = *(const bf16x8*)&As[p * 2048 + (wm * 32 + i * 16 + l16) * 32 + sl];
#pragma unroll
      for (int j = 0; j < 4; ++j)
        bfr[p][j] = *(const bf16x8*)&Bs[p * 4096 + (wn * 64 + j * 16 + l16) * 32 + sl];
    }
#pragma unroll
    for (int mi = 0; mi < 2; ++mi)
#pragma unroll
      for (int ni = 0; ni < 4; ++ni) {
        f32x4 a = acc[mi][ni];
        a = __builtin_amdgcn_mfma_f32_16x16x32_bf16(af[0][mi], bfr[0][ni], a, 0, 0, 0); // hh
        a = __builtin_amdgcn_mfma_f32_16x16x32_bf16(af[0][mi], bfr[1][ni], a, 0, 0, 0); // hm
        a = __builtin_amdgcn_mfma_f32_16x16x32_bf16(af[1][mi], bfr[0][ni], a, 0, 0, 0); // mh
        a = __builtin_amdgcn_mfma_f32_16x16x32_bf16(af[1][mi], bfr[1][ni], a, 0, 0, 0); // mm
        acc[mi][ni] = a;
      }
    __syncthreads();
  }
#pragma unroll
  for (int mi = 0; mi < 2; ++mi)
#pragma unroll
    for (int ni = 0; ni < 4; ++ni)
#pragma unroll
      for (int r = 0; r < 4; ++r) {
        int row = m0 + wm * 32 + mi * 16 + quad * 4 + r;
        int col = n0 + wn * 64 + ni * 16 + l16;
        C[(size_t)row * 1024 + col] = acc[mi][ni][r];
      }
}

// ---------------- qrep GEMM ----------------
__global__ __launch_bounds__(256) void qrep_gemm(const float* xrep, const float* wq, float* qparts) {
  int n0 = blockIdx.x * 32;
  int p  = blockIdx.y;
  int k0 = p * 128;
  int tid = threadIdx.x;
  __shared__ float xs[32 * 132];
  __shared__ float wsm[128 * 36];
#pragma unroll
  for (int i = 0; i < 4; ++i) {
    int c = tid + 256 * i;
    int m = c >> 5, kc = (c & 31) * 4;
    *(f32x4*)&xs[m * 132 + kc] = *(const f32x4*)&xrep[(size_t)m * 1024 + k0 + kc];
  }
#pragma unroll
  for (int i = 0; i < 4; ++i) {
    int c = tid + 256 * i;
    int k = c >> 3, n = (c & 7) * 4;
    *(f32x4*)&wsm[k * 36 + n] = *(const f32x4*)&wq[(size_t)(k0 + k) * 1024 + n0 + n];
  }
  __syncthreads();
#pragma unroll
  for (int i = 0; i < 4; ++i) {
    int o = tid + 256 * i;
    int m = o >> 5, n = o & 31;
    float acc = 0.f;
#pragma unroll 16
    for (int k = 0; k < 128; ++k) acc += xs[m * 132 + k] * wsm[k * 36 + n];
    qparts[((size_t)p * 32 + m) * 1024 + n0 + n] = acc;
  }
}

__global__ __launch_bounds__(256) void qsum(const float* qparts, float* qrep) {
  int i = blockIdx.x * 256 + threadIdx.x;
  float s = 0.f;
#pragma unroll
  for (int p = 0; p < 8; ++p) s += qparts[(size_t)p * 32768 + i];
  qrep[i] = s;
}

// ---------------- RoPE + pack ----------------
__global__ __launch_bounds__(256) void rope_pack(const unsigned short* qkv, const float* cosb,
                                                 const float* sinb, unsigned short* q_bf,
                                                 unsigned short* k_bf, unsigned short* vT) {
  int h = blockIdx.y;
  int s0 = blockIdx.x * 64;
  int tid = threadIdx.x;
  __shared__ unsigned short vt[128 * 66];
  for (int idx = tid; idx < 4096; idx += 256) {
    int r = idx >> 6, j = idx & 63;
    int s = s0 + r;
    float c = cosb[s * 64 + j], sn = sinb[s * 64 + j];
    const unsigned short* row = qkv + (size_t)s * 3072 + h * 128;
    size_t ob = ((size_t)h * S_LEN + s) * 128;
    float a = bf2f(row[j]), b = bf2f(row[j + 64]);
    q_bf[ob + j]      = f2bf(a * c - b * sn);
    q_bf[ob + j + 64] = f2bf(b * c + a * sn);
    a = bf2f(row[1024 + j]); b = bf2f(row[1024 + j + 64]);
    k_bf[ob + j]      = f2bf(a * c - b * sn);
    k_bf[ob + j + 64] = f2bf(b * c + a * sn);
  }
  for (int idx = tid; idx < 8192; idx += 256) {
    int r = idx >> 7, d = idx & 127;
    vt[d * 66 + r] = qkv[(size_t)(s0 + r) * 3072 + 2048 + h * 128 + d];
  }
  __syncthreads();
  for (int idx = tid; idx < 8192; idx += 256) {
    int d = idx >> 6, c = idx & 63;
    vT[((size_t)h * 128 + d) * S_LEN + s0 + c] = vt[d * 66 + c];
  }
}

// ---------------- in-place RoPE on fp32 K ----------------
__global__ __launch_bounds__(256) void rope_k_kernel(float* kf, const float* cosb, const float* sinb) {
  int idx = blockIdx.x * 256 + threadIdx.x;
  int s = idx >> 9;
  int rem = idx & 511;
  int h = rem >> 6, j = rem & 63;
  float c = cosb[s * 64 + j], sn = sinb[s * 64 + j];
  size_t e1 = (size_t)s * 1024 + h * 128 + j;
  float a = kf[e1], b = kf[e1 + 64];
  kf[e1]      = a * c - b * sn;
  kf[e1 + 64] = b * c + a * sn;
}

// ---------------- flash attention: Q64/K128, XCD-pinned, private-P (2 barriers/iter) ----------------
// grid (8 h, 64 y, 2 split); XCD = h; CU slot = y%32 pairs qt=c with qt=63-c. LDS 80KB.
__global__ __launch_bounds__(256) void flash_attn(const unsigned short* q_bf, const unsigned short* k_bf,
                                                  const unsigned short* vT, unsigned short* Opart,
                                                  float* mpart, float* lpart) {
  int h = blockIdx.x;
  int y = blockIdx.y;
  int qt = (y < 32) ? y : 95 - y;
  int split = blockIdx.z;
  int tid = threadIdx.x, w = tid >> 6, l = tid & 63, quad = l >> 4, l16 = l & 15;
  __shared__ unsigned short Ks[16384]; // K tile [kc4][key128][32dims] swizzled
  __shared__ unsigned short Vs[16384]; // V^T tile [kc4][d128][32keys] swizzled
  __shared__ unsigned short Ps[8192];  // per-wave P: [w][kc4][qr16][32keys] swizzled
  const unsigned short* qbase = q_bf + (size_t)h * S_LEN * 128;
  const unsigned short* kbase = k_bf + (size_t)h * S_LEN * 128;
  const unsigned short* vbase = vT + (size_t)h * 128 * S_LEN;
  int sl = (quad ^ ((l16 >> 1) & 3)) * 8;
  bf16x8 qf[4];
#pragma unroll
  for (int kc = 0; kc < 4; ++kc) {
    int row = qt * 64 + w * 16 + l16;
    qf[kc] = *(const bf16x8*)&qbase[(size_t)row * 128 + kc * 32 + quad * 8];
  }
  f32x4 z4 = {0.f, 0.f, 0.f, 0.f};
  f32x4 o[8];
#pragma unroll
  for (int i = 0; i < 8; ++i) o[i] = z4;
  float mrow[4], lrow[4];
#pragma unroll
  for (int r = 0; r < 4; ++r) { mrow[r] = -3e38f; lrow[r] = 0.f; }
  const float sc2 = 0.12751712f;  // (1/sqrt(128)) * log2(e)
  int niter = (qt >> 1) + 1;
  int jmax = niter - 1;
  int half0 = (niter + 1) >> 1;
  int jlo = split ? half0 : 0;
  int jhi = split ? niter : half0;
  for (int j = jlo; j < jhi; ++j) {
#pragma unroll
    for (int it = 0; it < 8; ++it) {
      int c = it * 256 + tid;
      int kc = c >> 9, cc = c & 511, rr = cc >> 2, sg = cc & 3;
      int sw = (sg ^ ((rr >> 1) & 3)) * 8;
      load_lds16(kbase + (size_t)(j * 128 + rr) * 128 + kc * 32 + sw,
                 &Ks[(it * 256 + (tid & 192)) * 8]);
      load_lds16(vbase + (size_t)rr * S_LEN + j * 128 + kc * 32 + sw,
                 &Vs[(it * 256 + (tid & 192)) * 8]);
    }
    __syncthreads();
    f32x4 sa[8];
#pragma unroll
    for (int i = 0; i < 8; ++i) sa[i] = z4;
#pragma unroll
    for (int kc = 0; kc < 4; ++kc) {
      bf16x8 kf[8];
#pragma unroll
      for (int ni = 0; ni < 8; ++ni)
        kf[ni] = *(const bf16x8*)&Ks[kc * 4096 + (ni * 16 + l16) * 32 + sl];
#pragma unroll
      for (int ni = 0; ni < 8; ++ni)
        sa[ni] = __builtin_amdgcn_mfma_f32_16x16x32_bf16(qf[kc], kf[ni], sa[ni], 0, 0, 0);
    }
    bool diag = (j == jmax);
    float rmax[4];
#pragma unroll
    for (int r = 0; r < 4; ++r) rmax[r] = -3e38f;
#pragma unroll
    for (int ni = 0; ni < 8; ++ni) {
      int key = j * 128 + ni * 16 + l16;
#pragma unroll
      for (int r = 0; r < 4; ++r) {
        int qrow = qt * 64 + w * 16 + quad * 4 + r;
        float v = sa[ni][r] * sc2;
        if (diag && key > qrow) v = -1e10f;
        sa[ni][r] = v;
        rmax[r] = fmaxf(rmax[r], v);
      }
    }
#pragma unroll
    for (int r = 0; r < 4; ++r) {
      float v = rmax[r];
      v = fmaxf(v, __shfl_xor(v, 1));
      v = fmaxf(v, __shfl_xor(v, 2));
      v = fmaxf(v, __shfl_xor(v, 4));
      v = fmaxf(v, __shfl_xor(v, 8));
      float mnew = fmaxf(mrow[r], v);
      float alpha = exp2f(mrow[r] - mnew);
      mrow[r] = mnew;
      float rsum = 0.f;
#pragma unroll
      for (int ni = 0; ni < 8; ++ni) {
        float p = exp2f(sa[ni][r] - mnew);
        sa[ni][r] = p;
        rsum += p;
      }
      rsum += __shfl_xor(rsum, 1);
      rsum += __shfl_xor(rsum, 2);
      rsum += __shfl_xor(rsum, 4);
      rsum += __shfl_xor(rsum, 8);
      lrow[r] = lrow[r] * alpha + rsum;
#pragma unroll
      for (int nd = 0; nd < 8; ++nd) o[nd][r] *= alpha;
    }
    // P -> private per-wave LDS region (no barrier needed)
#pragma unroll
    for (int ni = 0; ni < 8; ++ni) {
      int key = ni * 16 + l16, kc = key >> 5, col = key & 31;
#pragma unroll
      for (int r = 0; r < 4; ++r) {
        int qr = quad * 4 + r;
        int slot = (col >> 3) ^ ((qr >> 1) & 3);
        Ps[w * 2048 + kc * 512 + qr * 32 + slot * 8 + (col & 7)] = f2bf(sa[ni][r]);
      }
    }
#pragma unroll
    for (int kc = 0; kc < 4; ++kc) {
      bf16x8 pf = *(const bf16x8*)&Ps[w * 2048 + kc * 512 + l16 * 32 + sl];
#pragma unroll
      for (int nd = 0; nd < 8; ++nd) {
        bf16x8 vf = *(const bf16x8*)&Vs[kc * 4096 + (nd * 16 + l16) * 32 + sl];
        o[nd] = __builtin_amdgcn_mfma_f32_16x16x32_bf16(pf, vf, o[nd], 0, 0, 0);
      }
    }
    __syncthreads();  // protect Ks/Vs before next staging
  }
  size_t pbase = (size_t)(split * 8 + h) * 4096 + qt * 64;
#pragma unroll
  for (int r = 0; r < 4; ++r) {
    int lr = w * 16 + quad * 4 + r;
#pragma unroll
    for (int nd = 0; nd < 8; ++nd) {
      int d = nd * 16 + l16;
      Opart[(pbase + lr) * 128 + d] = f2bf(o[nd][r]);
    }
    if (l16 == 0) {
      mpart[pbase + lr] = mrow[r];
      lpart[pbase + lr] = lrow[r];
    }
  }
}

// ---------------- combine the two key-splits ----------------
__global__ __launch_bounds__(256) void combine(const unsigned short* Opart, const float* mpart,
                                               const float* lpart, unsigned short* attn) {
  int idx = blockIdx.x * 256 + threadIdx.x;  // 8*4096*128
  int h = idx >> 19;
  int rem = idx & 524287;
  int row = rem >> 7, d = rem & 127;
  int r0 = h * 4096 + row;
  int r1 = 32768 + r0;
  float m0 = mpart[r0], m1 = mpart[r1];
  float l0 = lpart[r0], l1 = lpart[r1];
  float m = fmaxf(m0, m1);
  float a0 = exp2f(m0 - m), a1 = exp2f(m1 - m);
  float o0 = bf2f(Opart[(size_t)r0 * 128 + d]);
  float o1 = bf2f(Opart[(size_t)r1 * 128 + d]);
  float denom = a0 * l0 + a1 * l1;
  attn[(size_t)row * 1024 + h * 128 + d] = f2bf((a0 * o0 + a1 * o1) / denom);
}

// ---------------- rep-logit tile scores (XCD-pinned: x = head) ----------------
__global__ __launch_bounds__(256) void rep_scores(const float* krope, const float* qrep,
                                                  const float* cosb, const float* sinb,
                                                  float* scores) {
  int h = blockIdx.x, tt = blockIdx.y;
  int tid = threadIdx.x;
  __shared__ float Kt[128 * 129];
  __shared__ float qv[32 * 128];
  __shared__ float lg[32 * 128];
  for (int idx = tid; idx < 16384; idx += 256) {
    int r = idx >> 7, c = idx & 127;
    Kt[r * 129 + c] = krope[(size_t)(tt * 128 + r) * 1024 + h * 128 + c];
  }
  for (int idx = tid; idx < 2048; idx += 256) {
    int rep = idx >> 6, j = idx & 63;
    int sq = rep * 128 + 127;
    float a = qrep[(size_t)rep * 1024 + h * 128 + j];
    float b = qrep[(size_t)rep * 1024 + h * 128 + j + 64];
    float c = cosb[sq * 64 + j], sn = sinb[sq * 64 + j];
    qv[rep * 128 + j]      = a * c - b * sn;
    qv[rep * 128 + j + 64] = b * c + a * sn;
  }
  __syncthreads();
  int key = tid >> 1, half = tid & 1;
  float kreg[64];
#pragma unroll
  for (int d = 0; d < 64; ++d) kreg[d] = Kt[key * 129 + half * 64 + d];
  for (int rep = 0; rep < 32; ++rep) {
    const float* q = &qv[rep * 128 + half * 64];
    float dot = 0.f;
#pragma unroll
    for (int d = 0; d < 64; ++d) dot += kreg[d] * q[d];
    dot += __shfl_xor(dot, 1);
    if (half == 0) lg[rep * 128 + key] = dot;
  }
  __syncthreads();
  int rep = tid >> 3, chunk = tid & 7;
  float m = -3e38f;
#pragma unroll
  for (int i = 0; i < 16; ++i) m = fmaxf(m, lg[rep * 128 + chunk * 16 + i]);
  m = fmaxf(m, __shfl_xor(m, 1));
  m = fmaxf(m, __shfl_xor(m, 2));
  m = fmaxf(m, __shfl_xor(m, 4));
  if (chunk == 0) scores[((size_t)h * 32 + rep) * 32 + tt] = m;
}

// ---------------- top-8 selection ----------------
__global__ __launch_bounds__(256) void select_topk(const float* scores, float* out_idx) {
  int tid = threadIdx.x;
  int h = tid >> 5, t = tid & 31;
  float vals[32];
#pragma unroll
  for (int tt = 0; tt < 32; ++tt)
    vals[tt] = (tt <= t) ? scores[((size_t)h * 32 + t) * 32 + tt] : -3.0e38f;
  int base = (h * 32 + t) * 8;
  for (int i = 0; i < 8; ++i) {
    float best = -3.4e38f;
    int bi = 0;
#pragma unroll
    for (int c = 0; c < 32; ++c)
      if (vals[c] > best) { best = vals[c]; bi = c; }
    out_idx[base + i] = (float)bi;
    vals[bi] = -3.4e38f;
  }
}

extern "C" void kernel_launch(void* const* d_in, const int* in_sizes, int n_in,
                              void* d_out, int out_size, void* d_ws, size_t ws_size,
                              hipStream_t stream) {
  (void)in_sizes; (void)n_in; (void)out_size; (void)ws_size;
  const float* x    = (const float*)d_in[0];
  const float* wq   = (const float*)d_in[1];
  const float* wk   = (const float*)d_in[2];
  const float* wv   = (const float*)d_in[3];
  const float* wo   = (const float*)d_in[4];
  const float* cosb = (const float*)d_in[5];
  const float* sinb = (const float*)d_in[6];
  float* out = (float*)d_out;
  char* ws = (char*)d_ws;

  unsigned short* x_bf   = (unsigned short*)(ws);              //  0 ..  8 MB (= xh plane)
  unsigned short* wT     = (unsigned short*)(ws + 8388608);    //  8 .. 14 MB
  unsigned short* woT    = (unsigned short*)(ws + 14680064);   // 14 .. 16 MB
  unsigned short* qkv_bf = (unsigned short*)(ws + 16777216);   // 16 .. 40 MB (dead after rope_pack)
  unsigned short* attn   = (unsigned short*)(ws + 16777216);   // 16 .. 24 MB
  unsigned short* Opart  = (unsigned short*)(ws + 25165824);   // 24 .. 40 MB (2x8x4096x128 bf16)
  unsigned short* q_bf   = (unsigned short*)(ws + 41943040);   // 40 .. 48 MB
  unsigned short* k_bf   = (unsigned short*)(ws + 50331648);   // 48 .. 56 MB
  unsigned short* vT     = (unsigned short*)(ws + 58720256);   // 56 .. 64 MB
  unsigned short* xm     = (unsigned short*)(ws + 41943040);   // transient, overlaps q_bf
  unsigned short* wkm    = (unsigned short*)(ws + 58720256);   // transient, overlaps vT
  float*          kf32   = (float*)(ws + 67108864);            // 64 .. 80 MB
  float*          xrep   = (float*)(ws + 83886080);            // 80.00 MB
  float*          qrep   = (float*)(ws + 84017152);            // 80.125 MB
  float*          qparts = (float*)(ws + 84148224);            // 80.25 .. 81.25 MB
  float*          scores = (float*)(ws + 85196800);            // 81.25 MB + 32 KB
  float*          mpart  = (float*)(ws + 85229568);            // +256 KB
  float*          lpart  = (float*)(ws + 85491712);            // +256 KB

  unsigned short* wkh = wT + (size_t)1 * 1024 * 1024;

  conv_w<<<dim3(32, 32, 4), 256, 0, stream>>>(wq, wk, wv, wo, wT, woT, wkm);
  conv_x<<<dim3(16384), 256, 0, stream>>>(x, x_bf, xm, xrep);
  gemm_bt<true><<<dim3(24, 32), 256, 0, stream>>>(x_bf, wT, qkv_bf, 3072);
  kexact<<<dim3(8, 64), 256, 0, stream>>>(x_bf, xm, wkh, wkm, kf32);
  qrep_gemm<<<dim3(32, 8), 256, 0, stream>>>(xrep, wq, qparts);
  qsum<<<dim3(128), 256, 0, stream>>>(qparts, qrep);
  rope_pack<<<dim3(64, 8), 256, 0, stream>>>(qkv_bf, cosb, sinb, q_bf, k_bf, vT);
  rope_k_kernel<<<dim3(8192), 256, 0, stream>>>(kf32, cosb, sinb);
  flash_attn<<<dim3(8, 64, 2), 256, 0, stream>>>(q_bf, k_bf, vT, Opart, mpart, lpart);
  combine<<<dim3(16384), 256, 0, stream>>>(Opart, mpart, lpart, attn);
  gemm_bt<false><<<dim3(8, 32), 256, 0, stream>>>(attn, woT, out, 1024);
  rep_scores<<<dim3(8, 32), 256, 0, stream>>>(kf32, qrep, cosb, sinb, scores);
  select_topk<<<dim3(1), 256, 0, stream>>>(scores, out + 4194304);
}

// Round 11
// 349.173 us; speedup vs baseline: 1.2843x; 1.0667x over previous
//
#include <hip/hip_runtime.h>
#include <hip/hip_bf16.h>
#include <stdint.h>

#define S_LEN 4096
#define EMB   1024
#define NH    8
#define HD    128

typedef __bf16 bf16x8 __attribute__((ext_vector_type(8)));
typedef float  f32x4  __attribute__((ext_vector_type(4)));
typedef short  s16x4  __attribute__((ext_vector_type(4)));

__device__ __forceinline__ unsigned short f2bf(float f) {
  unsigned int u = __float_as_uint(f);
  u += 0x7fffu + ((u >> 16) & 1u);
  return (unsigned short)(u >> 16);
}
__device__ __forceinline__ float bf2f(unsigned short u) {
  return __uint_as_float(((unsigned int)u) << 16);
}

typedef __attribute__((address_space(3))) void lds_void_t;
typedef const __attribute__((address_space(1))) void gbl_void_t;

__device__ __forceinline__ void load_lds16(const void* g, void* l) {
  __builtin_amdgcn_global_load_lds((gbl_void_t*)g, (lds_void_t*)l, 16, 0, 0);
}

// ---------------- weight transpose+convert: dst[n][k] = bf16(src[k][n]) ----------------
__global__ __launch_bounds__(256) void conv_w(const float* wq, const float* wk, const float* wv,
                                              const float* wo, unsigned short* wT, unsigned short* woT,
                                              unsigned short* wkm) {
  int z = blockIdx.z;
  const float* src = (z == 0) ? wq : (z == 1) ? wk : (z == 2) ? wv : wo;
  unsigned short* dst = (z == 3) ? woT : (wT + (size_t)z * 1024 * 1024);
  __shared__ float tl[32][33];
  int tx = threadIdx.x & 31, ty = threadIdx.x >> 5;
  int c0 = blockIdx.x * 32, r0 = blockIdx.y * 32;
#pragma unroll
  for (int i = 0; i < 4; ++i)
    tl[ty + 8 * i][tx] = src[(size_t)(r0 + ty + 8 * i) * 1024 + c0 + tx];
  __syncthreads();
#pragma unroll
  for (int i = 0; i < 4; ++i) {
    float v = tl[tx][ty + 8 * i];
    unsigned short h = f2bf(v);
    size_t o = (size_t)(c0 + ty + 8 * i) * 1024 + r0 + tx;
    dst[o] = h;
    if (z == 1) wkm[o] = f2bf(v - bf2f(h));
  }
}

// ---------------- x convert (2-plane split) + rep-row gather ----------------
__global__ __launch_bounds__(256) void conv_x(const float* x, unsigned short* xh, unsigned short* xm,
                                              float* xrep) {
  int idx = blockIdx.x * 256 + threadIdx.x;
  if (idx < 4194304) {
    float v = x[idx];
    unsigned short h = f2bf(v);
    xh[idx] = h;
    xm[idx] = f2bf(v - bf2f(h));
  }
  if (idx < 32768) {
    int r = idx >> 10, e = idx & 1023;
    xrep[idx] = x[(size_t)(r * 128 + 127) * 1024 + e];
  }
}

// ---------------- bf16 MFMA GEMM: C[M,N] = A[M,K=1024] * B[N,K=1024]^T ----------------
template <bool BF16OUT>
__global__ __launch_bounds__(256) void gemm_bt(const unsigned short* A, const unsigned short* B,
                                               void* Cv, int N) {
  __shared__ unsigned short Asm[4096];
  __shared__ unsigned short Bsm[4096];
  int tid = threadIdx.x;
  int w = tid >> 6, l = tid & 63, quad = l >> 4, l16 = l & 15;
  int wm = w >> 1, wn = w & 1;
  int m0 = blockIdx.y * 128, n0 = blockIdx.x * 128;
  f32x4 acc[4][4];
  f32x4 z4 = {0.f, 0.f, 0.f, 0.f};
#pragma unroll
  for (int i = 0; i < 4; ++i)
#pragma unroll
    for (int j = 0; j < 4; ++j) acc[i][j] = z4;
  const unsigned short* Ag = A + (size_t)m0 * 1024;
  const unsigned short* Bg = B + (size_t)n0 * 1024;
  int sl = (quad ^ ((l16 >> 1) & 3)) * 8;
  for (int kt = 0; kt < 1024; kt += 32) {
#pragma unroll
    for (int it = 0; it < 2; ++it) {
      int c = it * 256 + tid;
      int row = c >> 2, sg = c & 3;
      int sw = (sg ^ ((row >> 1) & 3)) * 8;
      load_lds16(Ag + (size_t)row * 1024 + kt + sw, &Asm[(it * 256 + (tid & 192)) * 8]);
      load_lds16(Bg + (size_t)row * 1024 + kt + sw, &Bsm[(it * 256 + (tid & 192)) * 8]);
    }
    __syncthreads();
    bf16x8 af[4], bfr[4];
#pragma unroll
    for (int i = 0; i < 4; ++i) {
      af[i]  = *(const bf16x8*)&Asm[(wm * 64 + i * 16 + l16) * 32 + sl];
      bfr[i] = *(const bf16x8*)&Bsm[(wn * 64 + i * 16 + l16) * 32 + sl];
    }
#pragma unroll
    for (int mi = 0; mi < 4; ++mi)
#pragma unroll
      for (int ni = 0; ni < 4; ++ni)
        acc[mi][ni] = __builtin_amdgcn_mfma_f32_16x16x32_bf16(af[mi], bfr[ni], acc[mi][ni], 0, 0, 0);
    __syncthreads();
  }
#pragma unroll
  for (int mi = 0; mi < 4; ++mi)
#pragma unroll
    for (int ni = 0; ni < 4; ++ni)
#pragma unroll
      for (int r = 0; r < 4; ++r) {
        int row = m0 + wm * 64 + mi * 16 + quad * 4 + r;
        int col = n0 + wn * 64 + ni * 16 + l16;
        if (BF16OUT)
          ((unsigned short*)Cv)[(size_t)row * N + col] = f2bf(acc[mi][ni][r]);
        else
          ((float*)Cv)[(size_t)row * N + col] = acc[mi][ni][r];
      }
}

// ---------------- exact K-GEMM via 2-plane bf16 split MFMA (hh+hm+mh+mm) ----------------
__global__ __launch_bounds__(256) void kexact(const unsigned short* Ah, const unsigned short* Am,
                                              const unsigned short* Bh, const unsigned short* Bm,
                                              float* C) {
  __shared__ unsigned short As[2 * 2048];
  __shared__ unsigned short Bs[2 * 4096];
  int tid = threadIdx.x;
  int w = tid >> 6, l = tid & 63, quad = l >> 4, l16 = l & 15;
  int wm = w >> 1, wn = w & 1;
  int m0 = blockIdx.y * 64, n0 = blockIdx.x * 128;
  f32x4 acc[2][4];
  f32x4 z4 = {0.f, 0.f, 0.f, 0.f};
#pragma unroll
  for (int i = 0; i < 2; ++i)
#pragma unroll
    for (int j = 0; j < 4; ++j) acc[i][j] = z4;
  const unsigned short* Aps[2] = {Ah + (size_t)m0 * 1024, Am + (size_t)m0 * 1024};
  const unsigned short* Bps[2] = {Bh + (size_t)n0 * 1024, Bm + (size_t)n0 * 1024};
  int arow = tid >> 2, asg = tid & 3;
  int asw = (asg ^ ((arow >> 1) & 3)) * 8;
  int sl = (quad ^ ((l16 >> 1) & 3)) * 8;
  for (int kt = 0; kt < 1024; kt += 32) {
#pragma unroll
    for (int p = 0; p < 2; ++p) {
      load_lds16(Aps[p] + (size_t)arow * 1024 + kt + asw, &As[p * 2048 + (tid & 192) * 8]);
#pragma unroll
      for (int it = 0; it < 2; ++it) {
        int c = it * 256 + tid;
        int row = c >> 2, sg = c & 3;
        int sw = (sg ^ ((row >> 1) & 3)) * 8;
        load_lds16(Bps[p] + (size_t)row * 1024 + kt + sw,
                   &Bs[p * 4096 + (it * 256 + (tid & 192)) * 8]);
      }
    }
    __syncthreads();
    bf16x8 af[2][2], bfr[2][4];
#pragma unroll
    for (int p = 0; p < 2; ++p) {
#pragma unroll
      for (int i = 0; i < 2; ++i)
        af[p][i] = *(const bf16x8*)&As[p * 2048 + (wm * 32 + i * 16 + l16) * 32 + sl];
#pragma unroll
      for (int j = 0; j < 4; ++j)
        bfr[p][j] = *(const bf16x8*)&Bs[p * 4096 + (wn * 64 + j * 16 + l16) * 32 + sl];
    }
#pragma unroll
    for (int mi = 0; mi < 2; ++mi)
#pragma unroll
      for (int ni = 0; ni < 4; ++ni) {
        f32x4 a = acc[mi][ni];
        a = __builtin_amdgcn_mfma_f32_16x16x32_bf16(af[0][mi], bfr[0][ni], a, 0, 0, 0); // hh
        a = __builtin_amdgcn_mfma_f32_16x16x32_bf16(af[0][mi], bfr[1][ni], a, 0, 0, 0); // hm
        a = __builtin_amdgcn_mfma_f32_16x16x32_bf16(af[1][mi], bfr[0][ni], a, 0, 0, 0); // mh
        a = __builtin_amdgcn_mfma_f32_16x16x32_bf16(af[1][mi], bfr[1][ni], a, 0, 0, 0); // mm
        acc[mi][ni] = a;
      }
    __syncthreads();
  }
#pragma unroll
  for (int mi = 0; mi < 2; ++mi)
#pragma unroll
    for (int ni = 0; ni < 4; ++ni)
#pragma unroll
      for (int r = 0; r < 4; ++r) {
        int row = m0 + wm * 32 + mi * 16 + quad * 4 + r;
        int col = n0 + wn * 64 + ni * 16 + l16;
        C[(size_t)row * 1024 + col] = acc[mi][ni][r];
      }
}

// ---------------- qrep GEMM ----------------
__global__ __launch_bounds__(256) void qrep_gemm(const float* xrep, const float* wq, float* qparts) {
  int n0 = blockIdx.x * 32;
  int p  = blockIdx.y;
  int k0 = p * 128;
  int tid = threadIdx.x;
  __shared__ float xs[32 * 132];
  __shared__ float wsm[128 * 36];
#pragma unroll
  for (int i = 0; i < 4; ++i) {
    int c = tid + 256 * i;
    int m = c >> 5, kc = (c & 31) * 4;
    *(f32x4*)&xs[m * 132 + kc] = *(const f32x4*)&xrep[(size_t)m * 1024 + k0 + kc];
  }
#pragma unroll
  for (int i = 0; i < 4; ++i) {
    int c = tid + 256 * i;
    int k = c >> 3, n = (c & 7) * 4;
    *(f32x4*)&wsm[k * 36 + n] = *(const f32x4*)&wq[(size_t)(k0 + k) * 1024 + n0 + n];
  }
  __syncthreads();
#pragma unroll
  for (int i = 0; i < 4; ++i) {
    int o = tid + 256 * i;
    int m = o >> 5, n = o & 31;
    float acc = 0.f;
#pragma unroll 16
    for (int k = 0; k < 128; ++k) acc += xs[m * 132 + k] * wsm[k * 36 + n];
    qparts[((size_t)p * 32 + m) * 1024 + n0 + n] = acc;
  }
}

__global__ __launch_bounds__(256) void qsum(const float* qparts, float* qrep) {
  int i = blockIdx.x * 256 + threadIdx.x;
  float s = 0.f;
#pragma unroll
  for (int p = 0; p < 8; ++p) s += qparts[(size_t)p * 32768 + i];
  qrep[i] = s;
}

// ---------------- RoPE + pack ----------------
__global__ __launch_bounds__(256) void rope_pack(const unsigned short* qkv, const float* cosb,
                                                 const float* sinb, unsigned short* q_bf,
                                                 unsigned short* k_bf, unsigned short* vT) {
  int h = blockIdx.y;
  int s0 = blockIdx.x * 64;
  int tid = threadIdx.x;
  __shared__ unsigned short vt[128 * 66];
  for (int idx = tid; idx < 4096; idx += 256) {
    int r = idx >> 6, j = idx & 63;
    int s = s0 + r;
    float c = cosb[s * 64 + j], sn = sinb[s * 64 + j];
    const unsigned short* row = qkv + (size_t)s * 3072 + h * 128;
    size_t ob = ((size_t)h * S_LEN + s) * 128;
    float a = bf2f(row[j]), b = bf2f(row[j + 64]);
    q_bf[ob + j]      = f2bf(a * c - b * sn);
    q_bf[ob + j + 64] = f2bf(b * c + a * sn);
    a = bf2f(row[1024 + j]); b = bf2f(row[1024 + j + 64]);
    k_bf[ob + j]      = f2bf(a * c - b * sn);
    k_bf[ob + j + 64] = f2bf(b * c + a * sn);
  }
  for (int idx = tid; idx < 8192; idx += 256) {
    int r = idx >> 7, d = idx & 127;
    vt[d * 66 + r] = qkv[(size_t)(s0 + r) * 3072 + 2048 + h * 128 + d];
  }
  __syncthreads();
  for (int idx = tid; idx < 8192; idx += 256) {
    int d = idx >> 6, c = idx & 63;
    vT[((size_t)h * 128 + d) * S_LEN + s0 + c] = vt[d * 66 + c];
  }
}

// ---------------- in-place RoPE on fp32 K ----------------
__global__ __launch_bounds__(256) void rope_k_kernel(float* kf, const float* cosb, const float* sinb) {
  int idx = blockIdx.x * 256 + threadIdx.x;
  int s = idx >> 9;
  int rem = idx & 511;
  int h = rem >> 6, j = rem & 63;
  float c = cosb[s * 64 + j], sn = sinb[s * 64 + j];
  size_t e1 = (size_t)s * 1024 + h * 128 + j;
  float a = kf[e1], b = kf[e1 + 64];
  kf[e1]      = a * c - b * sn;
  kf[e1 + 64] = b * c + a * sn;
}

// ---------------- flash attention: transposed-S, register P, K-tile 64, 4 blocks/CU ----------------
// grid (8 h, 64 y, 2 split); XCD = h; CU slot pairs qt=c with qt=63-c. LDS 32KB.
// S^T = K*Q^T via 16x16x32 (row=key, col=qrow); P stays in registers and feeds
// PV directly as the A-operand of 16x16x16 MFMA (A[m=l16=qrow][k=quad*4+r=key]).
__global__ __launch_bounds__(256, 4) void flash_attn(const unsigned short* q_bf,
                                                     const unsigned short* k_bf,
                                                     const unsigned short* vT,
                                                     unsigned short* Opart,
                                                     float* mpart, float* lpart) {
  int h = blockIdx.x;
  int y = blockIdx.y;
  int qt = (y < 32) ? y : 95 - y;
  int split = blockIdx.z;
  int tid = threadIdx.x, w = tid >> 6, l = tid & 63, quad = l >> 4, l16 = l & 15;
  __shared__ unsigned short Ks[8192]; // 16KB: [kc4(dim)][key64][32dims] swizzled
  __shared__ unsigned short Vs[8192]; // 16KB: [kc2(key)][d128][32keys] swizzled
  const unsigned short* qbase = q_bf + (size_t)h * S_LEN * 128;
  const unsigned short* kbase = k_bf + (size_t)h * S_LEN * 128;
  const unsigned short* vbase = vT + (size_t)h * 128 * S_LEN;
  int sl = (quad ^ ((l16 >> 1) & 3)) * 8;
  int qrow = qt * 64 + w * 16 + l16;
  bf16x8 qf[4];
#pragma unroll
  for (int kc = 0; kc < 4; ++kc)
    qf[kc] = *(const bf16x8*)&qbase[(size_t)qrow * 128 + kc * 32 + quad * 8];
  f32x4 z4 = {0.f, 0.f, 0.f, 0.f};
  f32x4 o[8];
#pragma unroll
  for (int i = 0; i < 8; ++i) o[i] = z4;
  float mrow = -3e38f, lrow = 0.f;
  const float sc2 = 0.12751712f;  // (1/sqrt(128)) * log2(e)
  int ntiles = qt + 1;            // 64-key tiles
  int half0 = (ntiles + 1) >> 1;
  int jlo = split ? half0 : 0;
  int jhi = split ? ntiles : half0;
  for (int j = jlo; j < jhi; ++j) {
    // stage K (16KB) + V^T (16KB)
#pragma unroll
    for (int it = 0; it < 4; ++it) {
      int c = it * 256 + tid;
      int kc = c >> 8, cc = c & 255, key = cc >> 2, sg = cc & 3;
      int sw = (sg ^ ((key >> 1) & 3)) * 8;
      load_lds16(kbase + (size_t)(j * 64 + key) * 128 + kc * 32 + sw,
                 &Ks[(it * 256 + (tid & 192)) * 8]);
      int kcv = c >> 9, ccv = c & 511, d = ccv >> 2, sgv = c & 3;
      int swv = (sgv ^ ((d >> 1) & 3)) * 8;
      load_lds16(vbase + (size_t)d * S_LEN + j * 64 + kcv * 32 + swv,
                 &Vs[(it * 256 + (tid & 192)) * 8]);
    }
    __syncthreads();
    // S^T = K * Q^T : sa[ni] rows=keys ni*16+quad*4+r, col=qrow(l16)
    f32x4 sa[4];
#pragma unroll
    for (int i = 0; i < 4; ++i) sa[i] = z4;
#pragma unroll
    for (int kc = 0; kc < 4; ++kc) {
#pragma unroll
      for (int ni = 0; ni < 4; ++ni) {
        bf16x8 kf = *(const bf16x8*)&Ks[kc * 2048 + (ni * 16 + l16) * 32 + sl];
        sa[ni] = __builtin_amdgcn_mfma_f32_16x16x32_bf16(kf, qf[kc], sa[ni], 0, 0, 0);
      }
    }
    bool diag = (j == qt);
    float vmax = -3e38f;
#pragma unroll
    for (int ni = 0; ni < 4; ++ni)
#pragma unroll
      for (int r = 0; r < 4; ++r) {
        int key = j * 64 + ni * 16 + quad * 4 + r;
        float v = sa[ni][r] * sc2;
        if (diag && key > qrow) v = -1e10f;
        sa[ni][r] = v;
        vmax = fmaxf(vmax, v);
      }
    vmax = fmaxf(vmax, __shfl_xor(vmax, 16));
    vmax = fmaxf(vmax, __shfl_xor(vmax, 32));
    float mnew = fmaxf(mrow, vmax);
    float alpha = exp2f(mrow - mnew);
    mrow = mnew;
    float rsum = 0.f;
#pragma unroll
    for (int ni = 0; ni < 4; ++ni)
#pragma unroll
      for (int r = 0; r < 4; ++r) {
        float p = exp2f(sa[ni][r] - mnew);
        sa[ni][r] = p;
        rsum += p;
      }
    rsum += __shfl_xor(rsum, 16);
    rsum += __shfl_xor(rsum, 32);
    lrow = lrow * alpha + rsum;
    float ar[4];
#pragma unroll
    for (int r = 0; r < 4; ++r) ar[r] = __shfl(alpha, quad * 4 + r);
#pragma unroll
    for (int nd = 0; nd < 8; ++nd)
#pragma unroll
      for (int r = 0; r < 4; ++r) o[nd][r] *= ar[r];
    // PV: P (registers) x V via 16x16x16; o rows=qrow(quad*4+r), cols=d(l16)
#pragma unroll
    for (int ni = 0; ni < 4; ++ni) {
      s16x4 pf;
#pragma unroll
      for (int r = 0; r < 4; ++r) pf[r] = (short)f2bf(sa[ni][r]);
      int chunk8 = (ni & 1) * 2 + (quad >> 1);
      int sub = (quad & 1) * 4;
      int kcv = ni >> 1;
#pragma unroll
      for (int nd = 0; nd < 8; ++nd) {
        int d = nd * 16 + l16;
        int slot = chunk8 ^ ((d >> 1) & 3);
        s16x4 vf = *(const s16x4*)&Vs[kcv * 4096 + d * 32 + slot * 8 + sub];
        o[nd] = __builtin_amdgcn_mfma_f32_16x16x16bf16_1k(pf, vf, o[nd], 0, 0, 0);
      }
    }
    __syncthreads();  // protect Ks/Vs before next staging
  }
  float mr[4], lr[4];
#pragma unroll
  for (int r = 0; r < 4; ++r) {
    mr[r] = __shfl(mrow, quad * 4 + r);
    lr[r] = __shfl(lrow, quad * 4 + r);
  }
  size_t pbase = (size_t)(split * 8 + h) * 4096 + qt * 64;
#pragma unroll
  for (int r = 0; r < 4; ++r) {
    int lrw = w * 16 + quad * 4 + r;
#pragma unroll
    for (int nd = 0; nd < 8; ++nd)
      Opart[(pbase + lrw) * 128 + nd * 16 + l16] = f2bf(o[nd][r]);
    if (l16 == 0) {
      mpart[pbase + lrw] = mr[r];
      lpart[pbase + lrw] = lr[r];
    }
  }
}

// ---------------- combine the two key-splits ----------------
__global__ __launch_bounds__(256) void combine(const unsigned short* Opart, const float* mpart,
                                               const float* lpart, unsigned short* attn) {
  int idx = blockIdx.x * 256 + threadIdx.x;  // 8*4096*128
  int h = idx >> 19;
  int rem = idx & 524287;
  int row = rem >> 7, d = rem & 127;
  int r0 = h * 4096 + row;
  int r1 = 32768 + r0;
  float m0 = mpart[r0], m1 = mpart[r1];
  float l0 = lpart[r0], l1 = lpart[r1];
  float m = fmaxf(m0, m1);
  float a0 = exp2f(m0 - m), a1 = exp2f(m1 - m);
  float o0 = bf2f(Opart[(size_t)r0 * 128 + d]);
  float o1 = bf2f(Opart[(size_t)r1 * 128 + d]);
  float denom = a0 * l0 + a1 * l1;
  attn[(size_t)row * 1024 + h * 128 + d] = f2bf((a0 * o0 + a1 * o1) / denom);
}

// ---------------- rep-logit tile scores (XCD-pinned: x = head) ----------------
__global__ __launch_bounds__(256) void rep_scores(const float* krope, const float* qrep,
                                                  const float* cosb, const float* sinb,
                                                  float* scores) {
  int h = blockIdx.x, tt = blockIdx.y;
  int tid = threadIdx.x;
  __shared__ float Kt[128 * 129];
  __shared__ float qv[32 * 128];
  __shared__ float lg[32 * 128];
  for (int idx = tid; idx < 16384; idx += 256) {
    int r = idx >> 7, c = idx & 127;
    Kt[r * 129 + c] = krope[(size_t)(tt * 128 + r) * 1024 + h * 128 + c];
  }
  for (int idx = tid; idx < 2048; idx += 256) {
    int rep = idx >> 6, j = idx & 63;
    int sq = rep * 128 + 127;
    float a = qrep[(size_t)rep * 1024 + h * 128 + j];
    float b = qrep[(size_t)rep * 1024 + h * 128 + j + 64];
    float c = cosb[sq * 64 + j], sn = sinb[sq * 64 + j];
    qv[rep * 128 + j]      = a * c - b * sn;
    qv[rep * 128 + j + 64] = b * c + a * sn;
  }
  __syncthreads();
  int key = tid >> 1, half = tid & 1;
  float kreg[64];
#pragma unroll
  for (int d = 0; d < 64; ++d) kreg[d] = Kt[key * 129 + half * 64 + d];
  for (int rep = 0; rep < 32; ++rep) {
    const float* q = &qv[rep * 128 + half * 64];
    float dot = 0.f;
#pragma unroll
    for (int d = 0; d < 64; ++d) dot += kreg[d] * q[d];
    dot += __shfl_xor(dot, 1);
    if (half == 0) lg[rep * 128 + key] = dot;
  }
  __syncthreads();
  int rep = tid >> 3, chunk = tid & 7;
  float m = -3e38f;
#pragma unroll
  for (int i = 0; i < 16; ++i) m = fmaxf(m, lg[rep * 128 + chunk * 16 + i]);
  m = fmaxf(m, __shfl_xor(m, 1));
  m = fmaxf(m, __shfl_xor(m, 2));
  m = fmaxf(m, __shfl_xor(m, 4));
  if (chunk == 0) scores[((size_t)h * 32 + rep) * 32 + tt] = m;
}

// ---------------- top-8 selection ----------------
__global__ __launch_bounds__(256) void select_topk(const float* scores, float* out_idx) {
  int tid = threadIdx.x;
  int h = tid >> 5, t = tid & 31;
  float vals[32];
#pragma unroll
  for (int tt = 0; tt < 32; ++tt)
    vals[tt] = (tt <= t) ? scores[((size_t)h * 32 + t) * 32 + tt] : -3.0e38f;
  int base = (h * 32 + t) * 8;
  for (int i = 0; i < 8; ++i) {
    float best = -3.4e38f;
    int bi = 0;
#pragma unroll
    for (int c = 0; c < 32; ++c)
      if (vals[c] > best) { best = vals[c]; bi = c; }
    out_idx[base + i] = (float)bi;
    vals[bi] = -3.4e38f;
  }
}

extern "C" void kernel_launch(void* const* d_in, const int* in_sizes, int n_in,
                              void* d_out, int out_size, void* d_ws, size_t ws_size,
                              hipStream_t stream) {
  (void)in_sizes; (void)n_in; (void)out_size; (void)ws_size;
  const float* x    = (const float*)d_in[0];
  const float* wq   = (const float*)d_in[1];
  const float* wk   = (const float*)d_in[2];
  const float* wv   = (const float*)d_in[3];
  const float* wo   = (const float*)d_in[4];
  const float* cosb = (const float*)d_in[5];
  const float* sinb = (const float*)d_in[6];
  float* out = (float*)d_out;
  char* ws = (char*)d_ws;

  unsigned short* x_bf   = (unsigned short*)(ws);              //  0 ..  8 MB (= xh plane)
  unsigned short* wT     = (unsigned short*)(ws + 8388608);    //  8 .. 14 MB
  unsigned short* woT    = (unsigned short*)(ws + 14680064);   // 14 .. 16 MB
  unsigned short* qkv_bf = (unsigned short*)(ws + 16777216);   // 16 .. 40 MB (dead after rope_pack)
  unsigned short* attn   = (unsigned short*)(ws + 16777216);   // 16 .. 24 MB
  unsigned short* Opart  = (unsigned short*)(ws + 25165824);   // 24 .. 40 MB (2x8x4096x128 bf16)
  unsigned short* q_bf   = (unsigned short*)(ws + 41943040);   // 40 .. 48 MB
  unsigned short* k_bf   = (unsigned short*)(ws + 50331648);   // 48 .. 56 MB
  unsigned short* vT     = (unsigned short*)(ws + 58720256);   // 56 .. 64 MB
  unsigned short* xm     = (unsigned short*)(ws + 41943040);   // transient, overlaps q_bf
  unsigned short* wkm    = (unsigned short*)(ws + 58720256);   // transient, overlaps vT
  float*          kf32   = (float*)(ws + 67108864);            // 64 .. 80 MB
  float*          xrep   = (float*)(ws + 83886080);            // 80.00 MB
  float*          qrep   = (float*)(ws + 84017152);            // 80.125 MB
  float*          qparts = (float*)(ws + 84148224);            // 80.25 .. 81.25 MB
  float*          scores = (float*)(ws + 85196800);            // 81.25 MB + 32 KB
  float*          mpart  = (float*)(ws + 85229568);            // +256 KB
  float*          lpart  = (float*)(ws + 85491712);            // +256 KB

  unsigned short* wkh = wT + (size_t)1 * 1024 * 1024;

  conv_w<<<dim3(32, 32, 4), 256, 0, stream>>>(wq, wk, wv, wo, wT, woT, wkm);
  conv_x<<<dim3(16384), 256, 0, stream>>>(x, x_bf, xm, xrep);
  gemm_bt<true><<<dim3(24, 32), 256, 0, stream>>>(x_bf, wT, qkv_bf, 3072);
  kexact<<<dim3(8, 64), 256, 0, stream>>>(x_bf, xm, wkh, wkm, kf32);
  qrep_gemm<<<dim3(32, 8), 256, 0, stream>>>(xrep, wq, qparts);
  qsum<<<dim3(128), 256, 0, stream>>>(qparts, qrep);
  rope_pack<<<dim3(64, 8), 256, 0, stream>>>(qkv_bf, cosb, sinb, q_bf, k_bf, vT);
  rope_k_kernel<<<dim3(8192), 256, 0, stream>>>(kf32, cosb, sinb);
  flash_attn<<<dim3(8, 64, 2), 256, 0, stream>>>(q_bf, k_bf, vT, Opart, mpart, lpart);
  combine<<<dim3(16384), 256, 0, stream>>>(Opart, mpart, lpart, attn);
  gemm_bt<false><<<dim3(8, 32), 256, 0, stream>>>(attn, woT, out, 1024);
  rep_scores<<<dim3(8, 32), 256, 0, stream>>>(kf32, qrep, cosb, sinb, scores);
  select_topk<<<dim3(1), 256, 0, stream>>>(scores, out + 4194304);
}